// Round 3
// baseline (5420.332 us; speedup 1.0000x reference)
//
#include <hip/hip_runtime.h>
#include <hip/hip_bf16.h>

typedef __bf16 bf16x8 __attribute__((ext_vector_type(8)));
typedef float  f32x4  __attribute__((ext_vector_type(4)));

#define DEV static __device__ __forceinline__

DEV float bf2f(ushort u) { unsigned x = ((unsigned)u) << 16; return __uint_as_float(x); }
DEV ushort f2bf(float f) {
    unsigned u = __float_as_uint(f);
    unsigned r = (u + 0x7FFFu + ((u >> 16) & 1u)) >> 16;  // RNE
    return (ushort)r;
}

// ---------------- fp32 -> bf16 weight conversion (one-time, tiny) ----------------
__global__ __launch_bounds__(256) void f2bf_kernel(
    const float* __restrict__ src, ushort* __restrict__ dst)
{
    int i = (blockIdx.x * 256 + threadIdx.x) * 4;
    float4 v = *(const float4*)(src + i);
    ushort4 o;
    o.x = f2bf(v.x); o.y = f2bf(v.y); o.z = f2bf(v.z); o.w = f2bf(v.w);
    *(ushort4*)(dst + i) = o;
}

// ---------------- pool (2x2 avg taps) + depthwise 3x3 + residual (one image) ----------------
// y[n_loc][256] bf16, n_loc = (lh*L + lw)*K*K + p*K + q ; one block per row, c = tid
template<int K, int L>
__global__ __launch_bounds__(256) void pool_dw_kernel(
    const float* __restrict__ x,    // [256][64][64] fp32 (one image)
    const float* __restrict__ w9,   // [256][9] fp32
    const float* __restrict__ bias, // [256] fp32
    ushort* __restrict__ y)         // bf16 out
{
    constexpr int NSP = K * K;
    int c = threadIdx.x;
    int n = blockIdx.x;
    int pos = n % NSP;
    int b = n / NSP;
    int p = pos / K, q = pos % K;
    int lw = b % L; int lh = b / L;
    const float* xb = x + (size_t)c * 4096;
    int row0 = lh * 4 - 1, col0 = lw * 4 - 1;  // orig coords of padded patch origin
    float pv[3][3];
#pragma unroll
    for (int dp = -1; dp <= 1; ++dp) {
#pragma unroll
        for (int dq = -1; dq <= 1; ++dq) {
            int pp = p + dp, qq = q + dq;
            float val = 0.f;
            if (pp >= 0 && pp < K && qq >= 0 && qq < K) {
                int r  = row0 + (pp * (K + 2)) / K;
                int cc = col0 + (qq * (K + 2)) / K;
                int r0 = min(max(r, 0), 63),     r1 = min(max(r + 1, 0), 63);
                int c0 = min(max(cc, 0), 63),    c1 = min(max(cc + 1, 0), 63);
                val = 0.25f * (xb[r0 * 64 + c0] + xb[r0 * 64 + c1] +
                               xb[r1 * 64 + c0] + xb[r1 * 64 + c1]);
            }
            pv[dp + 1][dq + 1] = val;
        }
    }
    float acc = pv[1][1] + bias[c];   // residual + conv bias
    const float* wc = w9 + c * 9;
#pragma unroll
    for (int i = 0; i < 9; ++i) acc += wc[i] * pv[i / 3][i % 3];
    y[(size_t)n * 256 + c] = f2bf(acc);
}

// ---------------- GEMM: OUT[n][ch] = sum_c ACT[n][c] * W[ch][c] (+bias), one image chunk ----------------
// EPI==0: store bf16 to out_bf[n][OC].
// EPI==1: scrambled fold-scatter (reference's raw reshape!) into acc[h][w][256] for this image.
//   pos = (n/K2)*256*K2 + ch*K2 + (n%K2); decode pos in base (C,K,K,L,L) as (c2,p2,q2,lh2,lw2);
//   scatter val/count -> acc[(lh2*4+p2)*64 + (lw2*4+q2)][c2].
template<int OC, int EPI, int K, int L>
__global__ __launch_bounds__(256) void gemm_kernel(
    const ushort* __restrict__ act,  // [Nchunk][256] bf16
    const ushort* __restrict__ w,    // [OC][256]  bf16 (pre-converted)
    const float* __restrict__ bias,  // [OC] fp32
    ushort* __restrict__ out_bf,
    float* __restrict__ out_acc)     // [64][64][256] fp32 (one image)
{
    __shared__ __attribute__((aligned(16))) ushort As[64][40];
    __shared__ __attribute__((aligned(16))) ushort Ws[64][40];
    const int tid  = threadIdx.x;
    const int n0   = blockIdx.x * 64;
    const int ch0  = blockIdx.y * 64;
    const int wv   = tid >> 6, lane = tid & 63;
    const int ar   = tid >> 2, acs = (tid & 3) * 8;
    f32x4 acc[4] = {};

    const ushort* aptr = act + (size_t)(n0 + ar) * 256 + acs;
    const ushort* wptr = w   + (size_t)(ch0 + ar) * 256 + acs;
    for (int k0 = 0; k0 < 256; k0 += 32) {
        *(uint4*)&As[ar][acs] = *(const uint4*)(aptr + k0);
        *(uint4*)&Ws[ar][acs] = *(const uint4*)(wptr + k0);
        __syncthreads();
        const int mrow = wv * 16 + (lane & 15);
        const int quad = lane >> 4;
        bf16x8 af = *(const bf16x8*)&As[mrow][quad * 8];
#pragma unroll
        for (int ct = 0; ct < 4; ++ct) {
            bf16x8 bfv = *(const bf16x8*)&Ws[ct * 16 + (lane & 15)][quad * 8];
            acc[ct] = __builtin_amdgcn_mfma_f32_16x16x32_bf16(af, bfv, acc[ct], 0, 0, 0);
        }
        __syncthreads();
    }
    const int colL  = lane & 15;
    const int rbase = wv * 16 + (lane >> 4) * 4;
#pragma unroll
    for (int ct = 0; ct < 4; ++ct) {
        int ch = ch0 + ct * 16 + colL;
        float bv = bias[ch];
#pragma unroll
        for (int r = 0; r < 4; ++r) {
            int n = n0 + rbase + r;
            float val = acc[ct][r] + bv;
            if (EPI == 0) {
                out_bf[(size_t)n * OC + ch] = f2bf(val);
            } else {
                constexpr int K2 = K * K;
                int b_loc = n / K2;
                int pq = n - b_loc * K2;
                int pos = (b_loc * 256 + ch) * K2 + pq;   // raw flat index within image
                int lw2 = pos % L; int t = pos / L;
                int lh2 = t % L;   t /= L;
                int q2 = t % K;    t /= K;
                int p2 = t % K;    int c2 = t / K;
                int h = lh2 * 4 + p2, wc = lw2 * 4 + q2;
                float inv = 1.f;
                if (K == 8) {
                    int loh = (h  >= 7) ? ((h  - 4) >> 2) : 0;
                    int hih = min(L - 1, h >> 2);
                    int low = (wc >= 7) ? ((wc - 4) >> 2) : 0;
                    int hiw = min(L - 1, wc >> 2);
                    inv = 1.f / (float)((hih - loh + 1) * (hiw - low + 1));
                }
                atomicAdd(out_acc + ((size_t)(h * 64 + wc)) * 256 + c2, val * inv);
            }
        }
    }
}

// ---------------- attention per (patch b, head h), one image chunk ----------------
template<int K>
__global__ __launch_bounds__(256) void attn_kernel(
    const ushort* __restrict__ qkv,  // [Bchunk*NSP][512] bf16
    const float* __restrict__ pe_w,  // [256][9] fp32
    const float* __restrict__ pe_b,  // [256] fp32
    ushort* __restrict__ o_out)      // [Bchunk*NSP][256] bf16
{
    constexpr int NSP = K * K;
    constexpr float SCALE = 0.17677669529663687f;  // 32^-0.5
    __shared__ float q_s[32][NSP];
    __shared__ float k_s[32][NSP];
    __shared__ float v_s[64][NSP + 1];
    __shared__ float S[NSP][NSP + 1];
    const int tid = threadIdx.x;
    const int h = blockIdx.x & 3;
    const int b = blockIdx.x >> 2;
    {
        int n0 = tid >> 4;
        int rr = (tid & 15) * 8;
        for (int nb = 0; nb < NSP; nb += 16) {
            int n = nb + n0;
            const ushort* src = qkv + (size_t)(b * NSP + n) * 512 + h * 128 + rr;
            uint4 pk = *(const uint4*)src;
            ushort us[8];
            *(uint4*)us = pk;
#pragma unroll
            for (int j = 0; j < 8; ++j) {
                int r = rr + j;
                float f = bf2f(us[j]);
                if (r < 32) q_s[r][n] = f * SCALE;
                else if (r < 64) k_s[r - 32][n] = f;
                else v_s[r - 64][n] = f;
            }
        }
    }
    __syncthreads();
    for (int idx = tid; idx < NSP * NSP; idx += 256) {
        int n = idx / NSP, m = idx % NSP;
        float a = 0.f;
#pragma unroll
        for (int d = 0; d < 32; ++d) a += q_s[d][n] * k_s[d][m];
        S[n][m] = a;
    }
    __syncthreads();
    for (int n = tid; n < NSP; n += 256) {
        float mx = -1e30f;
        for (int m = 0; m < NSP; ++m) mx = fmaxf(mx, S[n][m]);
        float sum = 0.f;
        for (int m = 0; m < NSP; ++m) { float e = __expf(S[n][m] - mx); S[n][m] = e; sum += e; }
        float inv = 1.f / sum;
        for (int m = 0; m < NSP; ++m) S[n][m] *= inv;
    }
    __syncthreads();
    for (int idx = tid; idx < 64 * NSP; idx += 256) {
        int d = idx & 63, n = idx >> 6;
        float a = 0.f;
        for (int m = 0; m < NSP; ++m) a += v_s[d][m] * S[n][m];
        int c = h * 64 + d;
        int p = n / K, q = n % K;
        float pe = pe_b[c];
        const float* wc = pe_w + c * 9;
#pragma unroll
        for (int dp = -1; dp <= 1; ++dp) {
#pragma unroll
            for (int dq = -1; dq <= 1; ++dq) {
                int pp = p + dp, qq = q + dq;
                if (pp >= 0 && pp < K && qq >= 0 && qq < K)
                    pe += wc[(dp + 1) * 3 + (dq + 1)] * v_s[d][pp * K + qq];
            }
        }
        o_out[(size_t)(b * NSP + n) * 256 + c] = f2bf(a + pe);
    }
}

// ---------------- final: out = (x + acc) / 3, transpose [n][h][w][c] -> [n][c][h][w] ----------------
__global__ __launch_bounds__(256) void final_kernel(
    const float* __restrict__ x, const float* __restrict__ acc,
    float* __restrict__ out)
{
    __shared__ __attribute__((aligned(16))) float tile[64][132];
    const int tid = threadIdx.x;
    const int bid = blockIdx.x;
    const int chalf = bid & 1;
    const int h = (bid >> 1) & 63;
    const int nn = bid >> 7;
    const int c0 = chalf * 128;
#pragma unroll
    for (int rep = 0; rep < 8; ++rep) {
        int vidx = rep * 256 + tid;
        int wq = vidx >> 5;
        int cv = (vidx & 31) * 4;
        const float* src = acc + ((size_t)((nn * 64 + h) * 64 + wq)) * 256 + c0 + cv;
        *(float4*)&tile[wq][cv] = *(const float4*)src;
    }
    __syncthreads();
    const float third = 1.f / 3.f;
#pragma unroll
    for (int rep = 0; rep < 8; ++rep) {
        int cl = rep * 16 + (tid >> 4);
        int c = c0 + cl;
        int w4 = (tid & 15) * 4;
        size_t off = ((size_t)((nn * 256 + c) * 64 + h)) * 64 + w4;
        float4 xv = *(const float4*)(x + off);
        float4 o;
        o.x = (xv.x + tile[w4 + 0][cl]) * third;
        o.y = (xv.y + tile[w4 + 1][cl]) * third;
        o.z = (xv.z + tile[w4 + 2][cl]) * third;
        o.w = (xv.w + tile[w4 + 3][cl]) * third;
        *(float4*)(out + off) = o;
    }
}

extern "C" void kernel_launch(void* const* d_in, const int* in_sizes, int n_in,
                              void* d_out, int out_size, void* d_ws, size_t ws_size,
                              hipStream_t stream)
{
    const float* x      = (const float*)d_in[0];
    const float* qkv_w  = (const float*)d_in[1];
    const float* qkv_b  = (const float*)d_in[2];
    const float* proj_w = (const float*)d_in[3];
    const float* proj_b = (const float*)d_in[4];
    const float* apw    = (const float*)d_in[5];
    const float* apb    = (const float*)d_in[6];
    const float* dpw    = (const float*)d_in[7];
    const float* dpb    = (const float*)d_in[8];
    float* out = (float*)d_out;

    // Per-image chunked workspace:
    //   acc  : 8 * 64*64*256 fp32            = 33,554,432 B
    //   ybuf : 14400 * 256 bf16 (max chunk)  =  7,372,800 B
    //   qbuf : 14400 * 512 bf16 (max chunk)  = 14,745,600 B
    //   wbuf : (512*256 + 256*256) bf16      =    393,216 B
    const size_t ACC_B = 8ull * 64 * 64 * 256 * 4;
    const size_t Y_B   = 14400ull * 256 * 2;
    const size_t Q_B   = 14400ull * 512 * 2;
    const size_t W_B   = (512ull * 256 + 256ull * 256) * 2;
    if (ws_size < ACC_B + Y_B + Q_B + W_B) {
        // finite sentinel (~1.27e4 fp32): "workspace too small", NOT a numerics bug
        hipMemsetAsync(d_out, 0x46, 4, stream);
        return;
    }
    float*  accb  = (float*)d_ws;
    ushort* ybuf  = (ushort*)((char*)d_ws + ACC_B);
    ushort* qbuf  = (ushort*)((char*)d_ws + ACC_B + Y_B);
    ushort* qw_bf = (ushort*)((char*)d_ws + ACC_B + Y_B + Q_B);
    ushort* pw_bf = qw_bf + 512 * 256;

    hipMemsetAsync(accb, 0, ACC_B, stream);
    f2bf_kernel<<<128, 256, 0, stream>>>(qkv_w, qw_bf);   // 512*256 = 131072 = 128*256*4
    f2bf_kernel<<<64, 256, 0, stream>>>(proj_w, pw_bf);   // 256*256 =  65536 =  64*256*4

    // K=8: L=15, per-image rows = 15*15*64 = 14400
    for (int nn = 0; nn < 8; ++nn) {
        const float* x_nn = x + (size_t)nn * 256 * 4096;
        float* acc_nn = accb + (size_t)nn * 64 * 64 * 256;
        pool_dw_kernel<8, 15><<<14400, 256, 0, stream>>>(x_nn, dpw, dpb, ybuf);
        gemm_kernel<512, 0, 8, 15><<<dim3(225, 8), 256, 0, stream>>>(ybuf, qw_bf, qkv_b, qbuf, nullptr);
        attn_kernel<8><<<900, 256, 0, stream>>>(qbuf, apw, apb, ybuf);
        gemm_kernel<256, 1, 8, 15><<<dim3(225, 4), 256, 0, stream>>>(ybuf, pw_bf, proj_b, nullptr, acc_nn);
    }
    // K=4: L=16, per-image rows = 16*16*16 = 4096
    for (int nn = 0; nn < 8; ++nn) {
        const float* x_nn = x + (size_t)nn * 256 * 4096;
        float* acc_nn = accb + (size_t)nn * 64 * 64 * 256;
        pool_dw_kernel<4, 16><<<4096, 256, 0, stream>>>(x_nn, dpw, dpb, ybuf);
        gemm_kernel<512, 0, 4, 16><<<dim3(64, 8), 256, 0, stream>>>(ybuf, qw_bf, qkv_b, qbuf, nullptr);
        attn_kernel<4><<<1024, 256, 0, stream>>>(qbuf, apw, apb, ybuf);
        gemm_kernel<256, 1, 4, 16><<<dim3(64, 4), 256, 0, stream>>>(ybuf, pw_bf, proj_b, nullptr, acc_nn);
    }

    final_kernel<<<1024, 256, 0, stream>>>(x, accb, out);
}

// Round 4
// 2555.494 us; speedup vs baseline: 2.1211x; 2.1211x over previous
//
#include <hip/hip_runtime.h>
#include <hip/hip_bf16.h>

typedef __bf16 bf16x8 __attribute__((ext_vector_type(8)));
typedef float  f32x4  __attribute__((ext_vector_type(4)));

#define DEV static __device__ __forceinline__

DEV float bf2f(ushort u) { unsigned x = ((unsigned)u) << 16; return __uint_as_float(x); }
DEV ushort f2bf(float f) {
    unsigned u = __float_as_uint(f);
    unsigned r = (u + 0x7FFFu + ((u >> 16) & 1u)) >> 16;  // RNE
    return (ushort)r;
}

// ---------------- fp32 -> bf16 weight conversion (one-time, tiny) ----------------
__global__ __launch_bounds__(256) void f2bf_kernel(
    const float* __restrict__ src, ushort* __restrict__ dst)
{
    int i = (blockIdx.x * 256 + threadIdx.x) * 4;
    float4 v = *(const float4*)(src + i);
    ushort4 o;
    o.x = f2bf(v.x); o.y = f2bf(v.y); o.z = f2bf(v.z); o.w = f2bf(v.w);
    *(ushort4*)(dst + i) = o;
}

// ---------------- box filter: B[g][br][bc][256] fp32, br,bc in [0,65) ----------------
// B[br][bc] = 0.25*(x[cl(br-1)][cl(bc-1)] + x[cl(br)][cl(bc-1)] + x[cl(br-1)][cl(bc)] + x[cl(br)][cl(bc)])
// Every pooled 2x2-avg tap (both K=4 and K=8) is a sample of B.
__global__ __launch_bounds__(256) void box_kernel(
    const float* __restrict__ x,   // [G][256][64][64] fp32 (group base)
    float* __restrict__ B)         // [G][65][65][256] fp32
{
    int br = blockIdx.x % 65; int g = blockIdx.x / 65;
    const float* xg = x + (size_t)g * 256 * 4096;
    float* Bg = B + (size_t)g * 65 * 65 * 256;
    const int r0 = max(br - 1, 0) * 64;
    const int r1 = min(br, 63) * 64;
    __shared__ float s[128][65];
    const int wl = threadIdx.x & 63, cq = threadIdx.x >> 6;   // load mapping
    const int c2 = threadIdx.x & 127, bh = threadIdx.x >> 7;  // store mapping
    for (int half = 0; half < 2; ++half) {
#pragma unroll 4
        for (int it = 0; it < 32; ++it) {
            int cl_ = it * 4 + cq;
            const float* xp = xg + (size_t)(half * 128 + cl_) * 4096;
            s[cl_][wl] = xp[r0 + wl] + xp[r1 + wl];
        }
        __syncthreads();
        for (int bc = bh; bc < 65; bc += 2) {
            float v = 0.25f * (s[c2][max(bc - 1, 0)] + s[c2][min(bc, 63)]);
            Bg[((size_t)br * 65 + bc) * 256 + half * 128 + c2] = v;
        }
        __syncthreads();
    }
}

// ---------------- pool gather + depthwise 3x3 + residual ----------------
// block = one patch (g, lh, lw); lane = channel. y[n][256], n = patch*K*K + p*K + q.
template<int K, int L>
__global__ __launch_bounds__(256) void pool_kernel(
    const float* __restrict__ B,    // [G][65][65][256] fp32
    const float* __restrict__ w9,   // [256][9] fp32
    const float* __restrict__ bias, // [256] fp32
    ushort* __restrict__ y)         // bf16 out
{
    constexpr int HF = K / 2;
    const int pk = blockIdx.x;
    const int lw = pk % L; int t = pk / L; const int lh = t % L; const int g = t / L;
    const int c = threadIdx.x;
    const float* Bg = B + (size_t)g * 65 * 65 * 256 + c;
    float pool[K][K];
#pragma unroll
    for (int p = 0; p < K; ++p) {
        const int br = lh * 4 + p + (p >= HF ? 1 : 0);
#pragma unroll
        for (int q = 0; q < K; ++q) {
            const int bc = lw * 4 + q + (q >= HF ? 1 : 0);
            pool[p][q] = Bg[((size_t)br * 65 + bc) * 256];
        }
    }
    float wv[9];
#pragma unroll
    for (int i = 0; i < 9; ++i) wv[i] = w9[c * 9 + i];
    const float bv = bias[c];
    ushort* yp = y + (size_t)pk * (K * K) * 256 + c;
#pragma unroll
    for (int p = 0; p < K; ++p) {
#pragma unroll
        for (int q = 0; q < K; ++q) {
            float a = pool[p][q] + bv;   // residual + conv bias
#pragma unroll
            for (int dp = -1; dp <= 1; ++dp) {
#pragma unroll
                for (int dq = -1; dq <= 1; ++dq) {
                    int pp = p + dp, qq = q + dq;
                    if (pp >= 0 && pp < K && qq >= 0 && qq < K)
                        a += wv[(dp + 1) * 3 + (dq + 1)] * pool[pp][qq];
                }
            }
            yp[(p * K + q) * 256] = f2bf(a);
        }
    }
}

// ---------------- GEMM: OUT[n][ch] = sum_c ACT[n][c] * W[ch][c] (+bias) ----------------
// grid = (OC/64, rowtiles). EPI==0: store bf16. EPI==1: scrambled fold-scatter into acc.
template<int OC, int EPI, int K, int L>
__global__ __launch_bounds__(256) void gemm_kernel(
    const ushort* __restrict__ act,  // [G*rows][256] bf16
    const ushort* __restrict__ w,    // [OC][256]  bf16
    const float* __restrict__ bias,  // [OC] fp32
    ushort* __restrict__ out_bf,
    float* __restrict__ out_acc)     // [G][64][64][256] fp32 (group base)
{
    __shared__ __attribute__((aligned(16))) ushort As[64][40];
    __shared__ __attribute__((aligned(16))) ushort Ws[64][40];
    const int tid  = threadIdx.x;
    const int ch0  = blockIdx.x * 64;
    const int n0   = blockIdx.y * 64;
    const int wv   = tid >> 6, lane = tid & 63;
    const int ar   = tid >> 2, acs = (tid & 3) * 8;
    f32x4 acc[4] = {};

    const ushort* aptr = act + (size_t)(n0 + ar) * 256 + acs;
    const ushort* wptr = w   + (size_t)(ch0 + ar) * 256 + acs;
    for (int k0 = 0; k0 < 256; k0 += 32) {
        *(uint4*)&As[ar][acs] = *(const uint4*)(aptr + k0);
        *(uint4*)&Ws[ar][acs] = *(const uint4*)(wptr + k0);
        __syncthreads();
        const int mrow = wv * 16 + (lane & 15);
        const int quad = lane >> 4;
        bf16x8 af = *(const bf16x8*)&As[mrow][quad * 8];
#pragma unroll
        for (int ct = 0; ct < 4; ++ct) {
            bf16x8 bfv = *(const bf16x8*)&Ws[ct * 16 + (lane & 15)][quad * 8];
            acc[ct] = __builtin_amdgcn_mfma_f32_16x16x32_bf16(af, bfv, acc[ct], 0, 0, 0);
        }
        __syncthreads();
    }
    const int colL  = lane & 15;
    const int rbase = wv * 16 + (lane >> 4) * 4;
#pragma unroll
    for (int ct = 0; ct < 4; ++ct) {
        int ch = ch0 + ct * 16 + colL;
        float bv = bias[ch];
#pragma unroll
        for (int r = 0; r < 4; ++r) {
            int n = n0 + rbase + r;
            float val = acc[ct][r] + bv;
            if (EPI == 0) {
                out_bf[(size_t)n * OC + ch] = f2bf(val);
            } else {
                constexpr int K2 = K * K;
                int b_g  = n / K2;
                int pq   = n - b_g * K2;
                int g    = b_g / (L * L);
                int b_loc = b_g - g * (L * L);
                int pos = (b_loc * 256 + ch) * K2 + pq;   // raw flat index within image
                int lw2 = pos % L; int t = pos / L;
                int lh2 = t % L;   t /= L;
                int q2 = t % K;    t /= K;
                int p2 = t % K;    int c2 = t / K;
                int h = lh2 * 4 + p2, wc = lw2 * 4 + q2;
                float inv = 1.f;
                if (K == 8) {
                    int loh = (h  >= 7) ? ((h  - 4) >> 2) : 0;
                    int hih = min(L - 1, h >> 2);
                    int low = (wc >= 7) ? ((wc - 4) >> 2) : 0;
                    int hiw = min(L - 1, wc >> 2);
                    inv = 1.f / (float)((hih - loh + 1) * (hiw - low + 1));
                }
                atomicAdd(out_acc + (size_t)g * 64 * 64 * 256 +
                          ((size_t)(h * 64 + wc)) * 256 + c2, val * inv);
            }
        }
    }
}

// ---------------- attention per (patch b, head h) ----------------
template<int K>
__global__ __launch_bounds__(256) void attn_kernel(
    const ushort* __restrict__ qkv,  // [G*rows][512] bf16
    const float* __restrict__ pe_w,  // [256][9] fp32
    const float* __restrict__ pe_b,  // [256] fp32
    ushort* __restrict__ o_out)      // [G*rows][256] bf16
{
    constexpr int NSP = K * K;
    constexpr float SCALE = 0.17677669529663687f;  // 32^-0.5
    __shared__ float q_s[32][NSP];
    __shared__ float k_s[32][NSP];
    __shared__ float v_s[64][NSP + 1];
    __shared__ float S[NSP][NSP + 1];
    const int tid = threadIdx.x;
    const int h = blockIdx.x & 3;
    const int b = blockIdx.x >> 2;
    {
        int n0 = tid >> 4;
        int rr = (tid & 15) * 8;
        for (int nb = 0; nb < NSP; nb += 16) {
            int n = nb + n0;
            const ushort* src = qkv + (size_t)(b * NSP + n) * 512 + h * 128 + rr;
            uint4 pk = *(const uint4*)src;
            ushort us[8];
            *(uint4*)us = pk;
#pragma unroll
            for (int j = 0; j < 8; ++j) {
                int r = rr + j;
                float f = bf2f(us[j]);
                if (r < 32) q_s[r][n] = f * SCALE;
                else if (r < 64) k_s[r - 32][n] = f;
                else v_s[r - 64][n] = f;
            }
        }
    }
    __syncthreads();
    for (int idx = tid; idx < NSP * NSP; idx += 256) {
        int n = idx / NSP, m = idx % NSP;
        float a = 0.f;
#pragma unroll
        for (int d = 0; d < 32; ++d) a += q_s[d][n] * k_s[d][m];
        S[n][m] = a;
    }
    __syncthreads();
    for (int n = tid; n < NSP; n += 256) {
        float mx = -1e30f;
        for (int m = 0; m < NSP; ++m) mx = fmaxf(mx, S[n][m]);
        float sum = 0.f;
        for (int m = 0; m < NSP; ++m) { float e = __expf(S[n][m] - mx); S[n][m] = e; sum += e; }
        float inv = 1.f / sum;
        for (int m = 0; m < NSP; ++m) S[n][m] *= inv;
    }
    __syncthreads();
    for (int idx = tid; idx < 64 * NSP; idx += 256) {
        int d = idx & 63, n = idx >> 6;
        float a = 0.f;
        for (int m = 0; m < NSP; ++m) a += v_s[d][m] * S[n][m];
        int c = h * 64 + d;
        int p = n / K, q = n % K;
        float pe = pe_b[c];
        const float* wc = pe_w + c * 9;
#pragma unroll
        for (int dp = -1; dp <= 1; ++dp) {
#pragma unroll
            for (int dq = -1; dq <= 1; ++dq) {
                int pp = p + dp, qq = q + dq;
                if (pp >= 0 && pp < K && qq >= 0 && qq < K)
                    pe += wc[(dp + 1) * 3 + (dq + 1)] * v_s[d][pp * K + qq];
            }
        }
        o_out[(size_t)(b * NSP + n) * 256 + c] = f2bf(a + pe);
    }
}

// ---------------- final: out = (x + acc) / 3, transpose [n][h][w][c] -> [n][c][h][w] ----------------
__global__ __launch_bounds__(256) void final_kernel(
    const float* __restrict__ x, const float* __restrict__ acc,
    float* __restrict__ out)
{
    __shared__ __attribute__((aligned(16))) float tile[64][132];
    const int tid = threadIdx.x;
    const int bid = blockIdx.x;
    const int chalf = bid & 1;
    const int h = (bid >> 1) & 63;
    const int nn = bid >> 7;
    const int c0 = chalf * 128;
#pragma unroll
    for (int rep = 0; rep < 8; ++rep) {
        int vidx = rep * 256 + tid;
        int wq = vidx >> 5;
        int cv = (vidx & 31) * 4;
        const float* src = acc + ((size_t)((nn * 64 + h) * 64 + wq)) * 256 + c0 + cv;
        *(float4*)&tile[wq][cv] = *(const float4*)src;
    }
    __syncthreads();
    const float third = 1.f / 3.f;
#pragma unroll
    for (int rep = 0; rep < 8; ++rep) {
        int cl = rep * 16 + (tid >> 4);
        int c = c0 + cl;
        int w4 = (tid & 15) * 4;
        size_t off = ((size_t)((nn * 256 + c) * 64 + h)) * 64 + w4;
        float4 xv = *(const float4*)(x + off);
        float4 o;
        o.x = (xv.x + tile[w4 + 0][cl]) * third;
        o.y = (xv.y + tile[w4 + 1][cl]) * third;
        o.z = (xv.z + tile[w4 + 2][cl]) * third;
        o.w = (xv.w + tile[w4 + 3][cl]) * third;
        *(float4*)(out + off) = o;
    }
}

extern "C" void kernel_launch(void* const* d_in, const int* in_sizes, int n_in,
                              void* d_out, int out_size, void* d_ws, size_t ws_size,
                              hipStream_t stream)
{
    const float* x      = (const float*)d_in[0];
    const float* qkv_w  = (const float*)d_in[1];
    const float* qkv_b  = (const float*)d_in[2];
    const float* proj_w = (const float*)d_in[3];
    const float* proj_b = (const float*)d_in[4];
    const float* apw    = (const float*)d_in[5];
    const float* apb    = (const float*)d_in[6];
    const float* dpw    = (const float*)d_in[7];
    const float* dpb    = (const float*)d_in[8];
    float* out = (float*)d_out;

    // Workspace: acc (33.5 MB) | weights bf16 (0.4 MB) | y (G*7.37 MB) | qkv (G*14.75 MB)
    // B (fp32 box image, G*4.33 MB) aliases the qkv region (disjoint live ranges).
    const size_t ACC_B = 8ull * 64 * 64 * 256 * 4;
    const size_t W_B   = (512ull * 256 + 256ull * 256) * 2;
    const size_t Y1    = 14400ull * 256 * 2;
    const size_t Q1    = 14400ull * 512 * 2;
    int G = 0;
    for (int g = 8; g >= 1; g >>= 1)
        if (ACC_B + W_B + (size_t)g * (Y1 + Q1) <= ws_size) { G = g; break; }
    if (!G) {
        hipMemsetAsync(d_out, 0x46, 4, stream);  // finite sentinel: ws too small
        return;
    }
    float*  accb  = (float*)d_ws;
    ushort* qw_bf = (ushort*)((char*)d_ws + ACC_B);
    ushort* pw_bf = qw_bf + 512 * 256;
    ushort* ybuf  = (ushort*)((char*)d_ws + ACC_B + W_B);
    ushort* qbuf  = (ushort*)((char*)ybuf + (size_t)G * Y1);
    float*  Bbuf  = (float*)qbuf;   // alias: B dead before qkv written

    hipMemsetAsync(accb, 0, ACC_B, stream);
    f2bf_kernel<<<128, 256, 0, stream>>>(qkv_w, qw_bf);
    f2bf_kernel<<<64, 256, 0, stream>>>(proj_w, pw_bf);

    for (int g0 = 0; g0 < 8; g0 += G) {
        const float* x_g = x + (size_t)g0 * 256 * 4096;
        float* acc_g = accb + (size_t)g0 * 64 * 64 * 256;
        // K=8 chain (L=15, 225 patches/img, 14400 rows/img)
        box_kernel<<<G * 65, 256, 0, stream>>>(x_g, Bbuf);
        pool_kernel<8, 15><<<G * 225, 256, 0, stream>>>(Bbuf, dpw, dpb, ybuf);
        gemm_kernel<512, 0, 8, 15><<<dim3(8, G * 225), 256, 0, stream>>>(ybuf, qw_bf, qkv_b, qbuf, nullptr);
        attn_kernel<8><<<G * 900, 256, 0, stream>>>(qbuf, apw, apb, ybuf);
        gemm_kernel<256, 1, 8, 15><<<dim3(4, G * 225), 256, 0, stream>>>(ybuf, pw_bf, proj_b, nullptr, acc_g);
        // K=4 chain (L=16, 256 patches/img, 4096 rows/img)
        box_kernel<<<G * 65, 256, 0, stream>>>(x_g, Bbuf);
        pool_kernel<4, 16><<<G * 256, 256, 0, stream>>>(Bbuf, dpw, dpb, ybuf);
        gemm_kernel<512, 0, 4, 16><<<dim3(8, G * 64), 256, 0, stream>>>(ybuf, qw_bf, qkv_b, qbuf, nullptr);
        attn_kernel<4><<<G * 1024, 256, 0, stream>>>(qbuf, apw, apb, ybuf);
        gemm_kernel<256, 1, 4, 16><<<dim3(4, G * 64), 256, 0, stream>>>(ybuf, pw_bf, proj_b, nullptr, acc_g);
    }

    final_kernel<<<1024, 256, 0, stream>>>(x, accb, out);
}

// Round 5
// 2090.106 us; speedup vs baseline: 2.5933x; 1.2227x over previous
//
#include <hip/hip_runtime.h>
#include <hip/hip_bf16.h>

typedef __bf16 bf16x8 __attribute__((ext_vector_type(8)));
typedef float  f32x4  __attribute__((ext_vector_type(4)));

#define DEV static __device__ __forceinline__

DEV float bf2f(ushort u) { unsigned x = ((unsigned)u) << 16; return __uint_as_float(x); }
DEV ushort f2bf(float f) {
    unsigned u = __float_as_uint(f);
    unsigned r = (u + 0x7FFFu + ((u >> 16) & 1u)) >> 16;  // RNE
    return (ushort)r;
}

// ---------------- fp32 -> bf16 weight conversion (one-time, tiny) ----------------
__global__ __launch_bounds__(256) void f2bf_kernel(
    const float* __restrict__ src, ushort* __restrict__ dst)
{
    int i = (blockIdx.x * 256 + threadIdx.x) * 4;
    float4 v = *(const float4*)(src + i);
    ushort4 o;
    o.x = f2bf(v.x); o.y = f2bf(v.y); o.z = f2bf(v.z); o.w = f2bf(v.w);
    *(ushort4*)(dst + i) = o;
}

// ---------------- box filter: B[g][br][bc][256] fp32, br,bc in [0,65) ----------------
__global__ __launch_bounds__(256) void box_kernel(
    const float* __restrict__ x,   // [G][256][64][64] fp32 (group base)
    float* __restrict__ B)         // [G][65][65][256] fp32
{
    int br = blockIdx.x % 65; int g = blockIdx.x / 65;
    const float* xg = x + (size_t)g * 256 * 4096;
    float* Bg = B + (size_t)g * 65 * 65 * 256;
    const int r0 = max(br - 1, 0) * 64;
    const int r1 = min(br, 63) * 64;
    __shared__ float s[128][65];
    const int wl = threadIdx.x & 63, cq = threadIdx.x >> 6;   // load mapping
    const int c2 = threadIdx.x & 127, bh = threadIdx.x >> 7;  // store mapping
    for (int half = 0; half < 2; ++half) {
#pragma unroll 4
        for (int it = 0; it < 32; ++it) {
            int cl_ = it * 4 + cq;
            const float* xp = xg + (size_t)(half * 128 + cl_) * 4096;
            s[cl_][wl] = xp[r0 + wl] + xp[r1 + wl];
        }
        __syncthreads();
        for (int bc = bh; bc < 65; bc += 2) {
            float v = 0.25f * (s[c2][max(bc - 1, 0)] + s[c2][min(bc, 63)]);
            Bg[((size_t)br * 65 + bc) * 256 + half * 128 + c2] = v;
        }
        __syncthreads();
    }
}

// ---------------- pool gather + depthwise 3x3 + residual ----------------
template<int K, int L>
__global__ __launch_bounds__(256) void pool_kernel(
    const float* __restrict__ B,    // [G][65][65][256] fp32
    const float* __restrict__ w9,   // [256][9] fp32
    const float* __restrict__ bias, // [256] fp32
    ushort* __restrict__ y)         // bf16 out
{
    constexpr int HF = K / 2;
    const int pk = blockIdx.x;
    const int lw = pk % L; int t = pk / L; const int lh = t % L; const int g = t / L;
    const int c = threadIdx.x;
    const float* Bg = B + (size_t)g * 65 * 65 * 256 + c;
    float pool[K][K];
#pragma unroll
    for (int p = 0; p < K; ++p) {
        const int br = lh * 4 + p + (p >= HF ? 1 : 0);
#pragma unroll
        for (int q = 0; q < K; ++q) {
            const int bc = lw * 4 + q + (q >= HF ? 1 : 0);
            pool[p][q] = Bg[((size_t)br * 65 + bc) * 256];
        }
    }
    float wv[9];
#pragma unroll
    for (int i = 0; i < 9; ++i) wv[i] = w9[c * 9 + i];
    const float bv = bias[c];
    ushort* yp = y + (size_t)pk * (K * K) * 256 + c;
#pragma unroll
    for (int p = 0; p < K; ++p) {
#pragma unroll
        for (int q = 0; q < K; ++q) {
            float a = pool[p][q] + bv;   // residual + conv bias
#pragma unroll
            for (int dp = -1; dp <= 1; ++dp) {
#pragma unroll
                for (int dq = -1; dq <= 1; ++dq) {
                    int pp = p + dp, qq = q + dq;
                    if (pp >= 0 && pp < K && qq >= 0 && qq < K)
                        a += wv[(dp + 1) * 3 + (dq + 1)] * pool[pp][qq];
                }
            }
            yp[(p * K + q) * 256] = f2bf(a);
        }
    }
}

// ---------------- GEMM: OUT[n][ch] = sum_c ACT[n][c] * W[ch][c] (+bias) ----------------
// EPI==0: store bf16 to out_bf[n][OC].
// EPI==1: scrambled fold-scatter into acc[g][c2][h][w] (output layout, L2-local window):
//   f = (b_loc*256 + ch)*K2 + pq; decode f in base (C,K,K,L,L) -> (c2,p2,q2,lh2,lw2);
//   atomicAdd(acc[g][c2][lh2*4+p2][lw2*4+q2], val/count).
template<int OC, int EPI, int K, int L>
__global__ __launch_bounds__(256) void gemm_kernel(
    const ushort* __restrict__ act,  // [G*rows][256] bf16
    const ushort* __restrict__ w,    // [OC][256]  bf16
    const float* __restrict__ bias,  // [OC] fp32
    ushort* __restrict__ out_bf,
    float* __restrict__ out_acc)     // [G][256][64][64] fp32 (group base)
{
    __shared__ __attribute__((aligned(16))) ushort As[64][40];
    __shared__ __attribute__((aligned(16))) ushort Ws[64][40];
    const int tid  = threadIdx.x;
    const int ch0  = blockIdx.x * 64;
    const int n0   = blockIdx.y * 64;
    const int wv   = tid >> 6, lane = tid & 63;
    const int ar   = tid >> 2, acs = (tid & 3) * 8;
    f32x4 acc[4] = {};

    const ushort* aptr = act + (size_t)(n0 + ar) * 256 + acs;
    const ushort* wptr = w   + (size_t)(ch0 + ar) * 256 + acs;
    for (int k0 = 0; k0 < 256; k0 += 32) {
        *(uint4*)&As[ar][acs] = *(const uint4*)(aptr + k0);
        *(uint4*)&Ws[ar][acs] = *(const uint4*)(wptr + k0);
        __syncthreads();
        const int mrow = wv * 16 + (lane & 15);
        const int quad = lane >> 4;
        bf16x8 af = *(const bf16x8*)&As[mrow][quad * 8];
#pragma unroll
        for (int ct = 0; ct < 4; ++ct) {
            bf16x8 bfv = *(const bf16x8*)&Ws[ct * 16 + (lane & 15)][quad * 8];
            acc[ct] = __builtin_amdgcn_mfma_f32_16x16x32_bf16(af, bfv, acc[ct], 0, 0, 0);
        }
        __syncthreads();
    }
    const int colL  = lane & 15;
    const int rbase = wv * 16 + (lane >> 4) * 4;
#pragma unroll
    for (int ct = 0; ct < 4; ++ct) {
        int ch = ch0 + ct * 16 + colL;
        float bv = bias[ch];
#pragma unroll
        for (int r = 0; r < 4; ++r) {
            int n = n0 + rbase + r;
            float val = acc[ct][r] + bv;
            if (EPI == 0) {
                out_bf[(size_t)n * OC + ch] = f2bf(val);
            } else {
                constexpr int K2 = K * K;
                int b_g   = n / K2;
                int pq    = n - b_g * K2;
                int g     = b_g / (L * L);
                int b_loc = b_g - g * (L * L);
                int f = (b_loc * 256 + ch) * K2 + pq;   // raw flat index within image
                // decode f in base (256, K, K, L, L)
                int c2 = f / (K2 * L * L);
                int rr = f - c2 * (K2 * L * L);
                int p2 = rr / (K * L * L);
                rr -= p2 * (K * L * L);
                int q2 = rr / (L * L);
                rr -= q2 * (L * L);
                int lh2 = rr / L;
                int lw2 = rr - lh2 * L;
                int h = lh2 * 4 + p2, wc = lw2 * 4 + q2;
                float inv = 1.f;
                if (K == 8) {
                    int loh = (h  >= 7) ? ((h  - 4) >> 2) : 0;
                    int hih = min(L - 1, h >> 2);
                    int low = (wc >= 7) ? ((wc - 4) >> 2) : 0;
                    int hiw = min(L - 1, wc >> 2);
                    inv = 1.f / (float)((hih - loh + 1) * (hiw - low + 1));
                }
                atomicAdd(out_acc + (size_t)g * 256 * 4096 +
                          (size_t)c2 * 4096 + h * 64 + wc, val * inv);
            }
        }
    }
}

// ---------------- attention per (patch b, head h) ----------------
template<int K>
__global__ __launch_bounds__(256) void attn_kernel(
    const ushort* __restrict__ qkv,  // [G*rows][512] bf16
    const float* __restrict__ pe_w,  // [256][9] fp32
    const float* __restrict__ pe_b,  // [256] fp32
    ushort* __restrict__ o_out)      // [G*rows][256] bf16
{
    constexpr int NSP = K * K;
    constexpr float SCALE = 0.17677669529663687f;  // 32^-0.5
    __shared__ float q_s[32][NSP];
    __shared__ float k_s[32][NSP];
    __shared__ float v_s[64][NSP + 1];
    __shared__ float S[NSP][NSP + 1];
    const int tid = threadIdx.x;
    const int h = blockIdx.x & 3;
    const int b = blockIdx.x >> 2;
    {
        int n0 = tid >> 4;
        int rr = (tid & 15) * 8;
        for (int nb = 0; nb < NSP; nb += 16) {
            int n = nb + n0;
            const ushort* src = qkv + (size_t)(b * NSP + n) * 512 + h * 128 + rr;
            uint4 pk = *(const uint4*)src;
            ushort us[8];
            *(uint4*)us = pk;
#pragma unroll
            for (int j = 0; j < 8; ++j) {
                int r = rr + j;
                float f = bf2f(us[j]);
                if (r < 32) q_s[r][n] = f * SCALE;
                else if (r < 64) k_s[r - 32][n] = f;
                else v_s[r - 64][n] = f;
            }
        }
    }
    __syncthreads();
    for (int idx = tid; idx < NSP * NSP; idx += 256) {
        int n = idx / NSP, m = idx % NSP;
        float a = 0.f;
#pragma unroll
        for (int d = 0; d < 32; ++d) a += q_s[d][n] * k_s[d][m];
        S[n][m] = a;
    }
    __syncthreads();
    for (int n = tid; n < NSP; n += 256) {
        float mx = -1e30f;
        for (int m = 0; m < NSP; ++m) mx = fmaxf(mx, S[n][m]);
        float sum = 0.f;
        for (int m = 0; m < NSP; ++m) { float e = __expf(S[n][m] - mx); S[n][m] = e; sum += e; }
        float inv = 1.f / sum;
        for (int m = 0; m < NSP; ++m) S[n][m] *= inv;
    }
    __syncthreads();
    for (int idx = tid; idx < 64 * NSP; idx += 256) {
        int d = idx & 63, n = idx >> 6;
        float a = 0.f;
        for (int m = 0; m < NSP; ++m) a += v_s[d][m] * S[n][m];
        int c = h * 64 + d;
        int p = n / K, q = n % K;
        float pe = pe_b[c];
        const float* wc = pe_w + c * 9;
#pragma unroll
        for (int dp = -1; dp <= 1; ++dp) {
#pragma unroll
            for (int dq = -1; dq <= 1; ++dq) {
                int pp = p + dp, qq = q + dq;
                if (pp >= 0 && pp < K && qq >= 0 && qq < K)
                    pe += wc[(dp + 1) * 3 + (dq + 1)] * v_s[d][pp * K + qq];
            }
        }
        o_out[(size_t)(b * NSP + n) * 256 + c] = f2bf(a + pe);
    }
}

// ---------------- final: out = (x + acc) / 3, both in [n][c][h][w] ----------------
__global__ __launch_bounds__(256) void final_kernel(
    const float* __restrict__ x, const float* __restrict__ acc,
    float* __restrict__ out)
{
    int i = (blockIdx.x * 256 + threadIdx.x) * 4;
    const float third = 1.f / 3.f;
    float4 xv = *(const float4*)(x + i);
    float4 av = *(const float4*)(acc + i);
    float4 o;
    o.x = (xv.x + av.x) * third;
    o.y = (xv.y + av.y) * third;
    o.z = (xv.z + av.z) * third;
    o.w = (xv.w + av.w) * third;
    *(float4*)(out + i) = o;
}

extern "C" void kernel_launch(void* const* d_in, const int* in_sizes, int n_in,
                              void* d_out, int out_size, void* d_ws, size_t ws_size,
                              hipStream_t stream)
{
    const float* x      = (const float*)d_in[0];
    const float* qkv_w  = (const float*)d_in[1];
    const float* qkv_b  = (const float*)d_in[2];
    const float* proj_w = (const float*)d_in[3];
    const float* proj_b = (const float*)d_in[4];
    const float* apw    = (const float*)d_in[5];
    const float* apb    = (const float*)d_in[6];
    const float* dpw    = (const float*)d_in[7];
    const float* dpb    = (const float*)d_in[8];
    float* out = (float*)d_out;

    // Workspace: acc (33.5 MB, [g][c][h][w]) | weights bf16 (0.4 MB) | y (G*7.37 MB) | qkv (G*14.75 MB)
    // B (fp32 box image, G*4.33 MB) aliases the qkv region (disjoint live ranges).
    const size_t ACC_B = 8ull * 64 * 64 * 256 * 4;
    const size_t W_B   = (512ull * 256 + 256ull * 256) * 2;
    const size_t Y1    = 14400ull * 256 * 2;
    const size_t Q1    = 14400ull * 512 * 2;
    int G = 0;
    for (int g = 8; g >= 1; g >>= 1)
        if (ACC_B + W_B + (size_t)g * (Y1 + Q1) <= ws_size) { G = g; break; }
    if (!G) {
        hipMemsetAsync(d_out, 0x46, 4, stream);  // finite sentinel: ws too small
        return;
    }
    float*  accb  = (float*)d_ws;
    ushort* qw_bf = (ushort*)((char*)d_ws + ACC_B);
    ushort* pw_bf = qw_bf + 512 * 256;
    ushort* ybuf  = (ushort*)((char*)d_ws + ACC_B + W_B);
    ushort* qbuf  = (ushort*)((char*)ybuf + (size_t)G * Y1);
    float*  Bbuf  = (float*)qbuf;   // alias: B dead before qkv written

    hipMemsetAsync(accb, 0, ACC_B, stream);
    f2bf_kernel<<<128, 256, 0, stream>>>(qkv_w, qw_bf);
    f2bf_kernel<<<64, 256, 0, stream>>>(proj_w, pw_bf);

    for (int g0 = 0; g0 < 8; g0 += G) {
        const float* x_g = x + (size_t)g0 * 256 * 4096;
        float* acc_g = accb + (size_t)g0 * 256 * 4096;
        // K=8 chain (L=15, 225 patches/img, 14400 rows/img)
        box_kernel<<<G * 65, 256, 0, stream>>>(x_g, Bbuf);
        pool_kernel<8, 15><<<G * 225, 256, 0, stream>>>(Bbuf, dpw, dpb, ybuf);
        gemm_kernel<512, 0, 8, 15><<<dim3(8, G * 225), 256, 0, stream>>>(ybuf, qw_bf, qkv_b, qbuf, nullptr);
        attn_kernel<8><<<G * 900, 256, 0, stream>>>(qbuf, apw, apb, ybuf);
        gemm_kernel<256, 1, 8, 15><<<dim3(4, G * 225), 256, 0, stream>>>(ybuf, pw_bf, proj_b, nullptr, acc_g);
        // K=4 chain (L=16, 256 patches/img, 4096 rows/img)
        box_kernel<<<G * 65, 256, 0, stream>>>(x_g, Bbuf);
        pool_kernel<4, 16><<<G * 256, 256, 0, stream>>>(Bbuf, dpw, dpb, ybuf);
        gemm_kernel<512, 0, 4, 16><<<dim3(8, G * 64), 256, 0, stream>>>(ybuf, qw_bf, qkv_b, qbuf, nullptr);
        attn_kernel<4><<<G * 1024, 256, 0, stream>>>(qbuf, apw, apb, ybuf);
        gemm_kernel<256, 1, 4, 16><<<dim3(4, G * 64), 256, 0, stream>>>(ybuf, pw_bf, proj_b, nullptr, acc_g);
    }

    final_kernel<<<8192, 256, 0, stream>>>(x, accb, out);
}

// Round 6
// 805.674 us; speedup vs baseline: 6.7277x; 2.5942x over previous
//
#include <hip/hip_runtime.h>
#include <hip/hip_bf16.h>

typedef __bf16 bf16x8 __attribute__((ext_vector_type(8)));
typedef float  f32x4  __attribute__((ext_vector_type(4)));

#define DEV static __device__ __forceinline__

DEV float bf2f(ushort u) { unsigned x = ((unsigned)u) << 16; return __uint_as_float(x); }
DEV ushort f2bf(float f) {
    unsigned u = __float_as_uint(f);
    unsigned r = (u + 0x7FFFu + ((u >> 16) & 1u)) >> 16;  // RNE
    return (ushort)r;
}

// ---------------- fp32 -> bf16 weight conversion (one-time, tiny) ----------------
__global__ __launch_bounds__(256) void f2bf_kernel(
    const float* __restrict__ src, ushort* __restrict__ dst)
{
    int i = (blockIdx.x * 256 + threadIdx.x) * 4;
    float4 v = *(const float4*)(src + i);
    ushort4 o;
    o.x = f2bf(v.x); o.y = f2bf(v.y); o.z = f2bf(v.z); o.w = f2bf(v.w);
    *(ushort4*)(dst + i) = o;
}

// ---------------- box filter: B[g][br][bc][256] fp32, br,bc in [0,65) ----------------
__global__ __launch_bounds__(256) void box_kernel(
    const float* __restrict__ x,   // [G][256][64][64] fp32 (group base)
    float* __restrict__ B)         // [G][65][65][256] fp32
{
    int br = blockIdx.x % 65; int g = blockIdx.x / 65;
    const float* xg = x + (size_t)g * 256 * 4096;
    float* Bg = B + (size_t)g * 65 * 65 * 256;
    const int r0 = max(br - 1, 0) * 64;
    const int r1 = min(br, 63) * 64;
    __shared__ float s[128][65];
    const int wl = threadIdx.x & 63, cq = threadIdx.x >> 6;   // load mapping
    const int c2 = threadIdx.x & 127, bh = threadIdx.x >> 7;  // store mapping
    for (int half = 0; half < 2; ++half) {
#pragma unroll 4
        for (int it = 0; it < 32; ++it) {
            int cl_ = it * 4 + cq;
            const float* xp = xg + (size_t)(half * 128 + cl_) * 4096;
            s[cl_][wl] = xp[r0 + wl] + xp[r1 + wl];
        }
        __syncthreads();
        for (int bc = bh; bc < 65; bc += 2) {
            float v = 0.25f * (s[c2][max(bc - 1, 0)] + s[c2][min(bc, 63)]);
            Bg[((size_t)br * 65 + bc) * 256 + half * 128 + c2] = v;
        }
        __syncthreads();
    }
}

// ---------------- pool gather + depthwise 3x3 + residual ----------------
template<int K, int L>
__global__ __launch_bounds__(256) void pool_kernel(
    const float* __restrict__ B,    // [G][65][65][256] fp32
    const float* __restrict__ w9,   // [256][9] fp32
    const float* __restrict__ bias, // [256] fp32
    ushort* __restrict__ y)         // bf16 out
{
    constexpr int HF = K / 2;
    const int pk = blockIdx.x;
    const int lw = pk % L; int t = pk / L; const int lh = t % L; const int g = t / L;
    const int c = threadIdx.x;
    const float* Bg = B + (size_t)g * 65 * 65 * 256 + c;
    float pool[K][K];
#pragma unroll
    for (int p = 0; p < K; ++p) {
        const int br = lh * 4 + p + (p >= HF ? 1 : 0);
#pragma unroll
        for (int q = 0; q < K; ++q) {
            const int bc = lw * 4 + q + (q >= HF ? 1 : 0);
            pool[p][q] = Bg[((size_t)br * 65 + bc) * 256];
        }
    }
    float wv[9];
#pragma unroll
    for (int i = 0; i < 9; ++i) wv[i] = w9[c * 9 + i];
    const float bv = bias[c];
    ushort* yp = y + (size_t)pk * (K * K) * 256 + c;
#pragma unroll
    for (int p = 0; p < K; ++p) {
#pragma unroll
        for (int q = 0; q < K; ++q) {
            float a = pool[p][q] + bv;   // residual + conv bias
#pragma unroll
            for (int dp = -1; dp <= 1; ++dp) {
#pragma unroll
                for (int dq = -1; dq <= 1; ++dq) {
                    int pp = p + dp, qq = q + dq;
                    if (pp >= 0 && pp < K && qq >= 0 && qq < K)
                        a += wv[(dp + 1) * 3 + (dq + 1)] * pool[pp][qq];
                }
            }
            yp[(p * K + q) * 256] = f2bf(a);
        }
    }
}

// ---------------- GEMM: OUT[n][ch] = sum_c ACT[n][c] * W[ch][c] (+bias) ----------------
// EPI==0: store bf16 row-major out_bf[n][OC].
// EPI==1: store bf16 in scrambled-f order: out_bf[g_local*256*K2*L*L + (b_loc*256+ch)*K2 + pq].
//         (NO atomics — the fold gather happens in final_kernel.)
template<int OC, int EPI, int K, int L>
__global__ __launch_bounds__(256) void gemm_kernel(
    const ushort* __restrict__ act,  // [rows][256] bf16
    const ushort* __restrict__ w,    // [OC][256]  bf16
    const float* __restrict__ bias,  // [OC] fp32
    ushort* __restrict__ out_bf)
{
    __shared__ __attribute__((aligned(16))) ushort As[64][40];
    __shared__ __attribute__((aligned(16))) ushort Ws[64][40];
    const int tid  = threadIdx.x;
    const int ch0  = blockIdx.x * 64;
    const int n0   = blockIdx.y * 64;
    const int wv   = tid >> 6, lane = tid & 63;
    const int ar   = tid >> 2, acs = (tid & 3) * 8;
    f32x4 acc[4] = {};

    const ushort* aptr = act + (size_t)(n0 + ar) * 256 + acs;
    const ushort* wptr = w   + (size_t)(ch0 + ar) * 256 + acs;
    for (int k0 = 0; k0 < 256; k0 += 32) {
        *(uint4*)&As[ar][acs] = *(const uint4*)(aptr + k0);
        *(uint4*)&Ws[ar][acs] = *(const uint4*)(wptr + k0);
        __syncthreads();
        const int mrow = wv * 16 + (lane & 15);
        const int quad = lane >> 4;
        bf16x8 af = *(const bf16x8*)&As[mrow][quad * 8];
#pragma unroll
        for (int ct = 0; ct < 4; ++ct) {
            bf16x8 bfv = *(const bf16x8*)&Ws[ct * 16 + (lane & 15)][quad * 8];
            acc[ct] = __builtin_amdgcn_mfma_f32_16x16x32_bf16(af, bfv, acc[ct], 0, 0, 0);
        }
        __syncthreads();
    }
    const int colL  = lane & 15;
    const int rbase = wv * 16 + (lane >> 4) * 4;
#pragma unroll
    for (int ct = 0; ct < 4; ++ct) {
        int ch = ch0 + ct * 16 + colL;
        float bv = bias[ch];
#pragma unroll
        for (int r = 0; r < 4; ++r) {
            int n = n0 + rbase + r;
            float val = acc[ct][r] + bv;
            if (EPI == 0) {
                out_bf[(size_t)n * OC + ch] = f2bf(val);
            } else {
                constexpr int K2 = K * K;
                constexpr int LL = L * L;
                int b_g   = n >> (K == 8 ? 6 : 4);
                int pq    = n & (K2 - 1);
                int gl    = b_g / LL;
                int b_loc = b_g - gl * LL;
                int f = (b_loc * 256 + ch) * K2 + pq;
                out_bf[(size_t)gl * (256 * K2 * LL) + f] = f2bf(val);
            }
        }
    }
}

// ---------------- attention per (patch b, head h) ----------------
template<int K>
__global__ __launch_bounds__(256) void attn_kernel(
    const ushort* __restrict__ qkv,  // [rows][512] bf16
    const float* __restrict__ pe_w,  // [256][9] fp32
    const float* __restrict__ pe_b,  // [256] fp32
    ushort* __restrict__ o_out)      // [rows][256] bf16
{
    constexpr int NSP = K * K;
    constexpr float SCALE = 0.17677669529663687f;  // 32^-0.5
    __shared__ float q_s[32][NSP];
    __shared__ float k_s[32][NSP];
    __shared__ float v_s[64][NSP + 1];
    __shared__ float S[NSP][NSP + 1];
    const int tid = threadIdx.x;
    const int h = blockIdx.x & 3;
    const int b = blockIdx.x >> 2;
    {
        int n0 = tid >> 4;
        int rr = (tid & 15) * 8;
        for (int nb = 0; nb < NSP; nb += 16) {
            int n = nb + n0;
            const ushort* src = qkv + (size_t)(b * NSP + n) * 512 + h * 128 + rr;
            uint4 pk = *(const uint4*)src;
            ushort us[8];
            *(uint4*)us = pk;
#pragma unroll
            for (int j = 0; j < 8; ++j) {
                int r = rr + j;
                float f = bf2f(us[j]);
                if (r < 32) q_s[r][n] = f * SCALE;
                else if (r < 64) k_s[r - 32][n] = f;
                else v_s[r - 64][n] = f;
            }
        }
    }
    __syncthreads();
    for (int idx = tid; idx < NSP * NSP; idx += 256) {
        int n = idx / NSP, m = idx % NSP;
        float a = 0.f;
#pragma unroll
        for (int d = 0; d < 32; ++d) a += q_s[d][n] * k_s[d][m];
        S[n][m] = a;
    }
    __syncthreads();
    for (int n = tid; n < NSP; n += 256) {
        float mx = -1e30f;
        for (int m = 0; m < NSP; ++m) mx = fmaxf(mx, S[n][m]);
        float sum = 0.f;
        for (int m = 0; m < NSP; ++m) { float e = __expf(S[n][m] - mx); S[n][m] = e; sum += e; }
        float inv = 1.f / sum;
        for (int m = 0; m < NSP; ++m) S[n][m] *= inv;
    }
    __syncthreads();
    for (int idx = tid; idx < 64 * NSP; idx += 256) {
        int d = idx & 63, n = idx >> 6;
        float a = 0.f;
        for (int m = 0; m < NSP; ++m) a += v_s[d][m] * S[n][m];
        int c = h * 64 + d;
        int p = n / K, q = n % K;
        float pe = pe_b[c];
        const float* wc = pe_w + c * 9;
#pragma unroll
        for (int dp = -1; dp <= 1; ++dp) {
#pragma unroll
            for (int dq = -1; dq <= 1; ++dq) {
                int pp = p + dp, qq = q + dq;
                if (pp >= 0 && pp < K && qq >= 0 && qq < K)
                    pe += wc[(dp + 1) * 3 + (dq + 1)] * v_s[d][pp * K + qq];
            }
        }
        o_out[(size_t)(b * NSP + n) * 256 + c] = f2bf(a + pe);
    }
}

// ---------------- final: out = (x + fold8(s8) + fold4(s4)) / 3 ----------------
// s8[g][f8], f8 = (((c2*8+p2)*8+q2)*15+lh2)*15+lw2 ; 1-4 contributions per pixel, / count.
// s4[g][f4], f4 = (((c2*4+p2)*4+q2)*16+lh2)*16+lw2 ; exact bijection (count 1).
__global__ __launch_bounds__(256) void final_kernel(
    const float* __restrict__ x,
    const ushort* __restrict__ s8,
    const ushort* __restrict__ s4,
    float* __restrict__ out)
{
    const int c2 = blockIdx.x & 255;
    const int g  = blockIdx.x >> 8;
    const ushort* s8g = s8 + (size_t)g * (256 * 64 * 225);
    const ushort* s4g = s4 + (size_t)g * (256 * 16 * 256);
    const float third = 1.f / 3.f;
#pragma unroll 2
    for (int it = 0; it < 16; ++it) {
        int pix = it * 256 + threadIdx.x;       // h*64 + w
        int h = pix >> 6, w = pix & 63;
        // K=4 (bijection)
        int f4 = ((((c2 * 4 + (h & 3)) * 4 + (w & 3)) * 16 + (h >> 2)) * 16) + (w >> 2);
        float v4 = bf2f(s4g[f4]);
        // K=8 (1-2 window positions per axis)
        int lh_lo = (h >= 8) ? ((h - 4) >> 2) : 0, lh_hi = min(14, h >> 2);
        int lw_lo = (w >= 8) ? ((w - 4) >> 2) : 0, lw_hi = min(14, w >> 2);
        float v8 = 0.f;
        for (int lh2 = lh_lo; lh2 <= lh_hi; ++lh2) {
            int p2 = h - lh2 * 4;
            for (int lw2 = lw_lo; lw2 <= lw_hi; ++lw2) {
                int q2 = w - lw2 * 4;
                int f8 = (((c2 * 8 + p2) * 8 + q2) * 15 + lh2) * 15 + lw2;
                v8 += bf2f(s8g[f8]);
            }
        }
        float inv = 1.f / (float)((lh_hi - lh_lo + 1) * (lw_hi - lw_lo + 1));
        size_t off = ((size_t)(g * 256 + c2)) * 4096 + pix;
        out[off] = (x[off] + v8 * inv + v4) * third;
    }
}

extern "C" void kernel_launch(void* const* d_in, const int* in_sizes, int n_in,
                              void* d_out, int out_size, void* d_ws, size_t ws_size,
                              hipStream_t stream)
{
    const float* x      = (const float*)d_in[0];
    const float* qkv_w  = (const float*)d_in[1];
    const float* qkv_b  = (const float*)d_in[2];
    const float* proj_w = (const float*)d_in[3];
    const float* proj_b = (const float*)d_in[4];
    const float* apw    = (const float*)d_in[5];
    const float* apb    = (const float*)d_in[6];
    const float* dpw    = (const float*)d_in[7];
    const float* dpb    = (const float*)d_in[8];
    float* out = (float*)d_out;

    // Workspace (no atomics, no fp32 accumulator):
    //   s8   : 8 img * 225*256*64 bf16 = 58,982,400 B   (scrambled proj8 output)
    //   s4   : 8 img * 256*256*16 bf16 = 16,777,216 B   (scrambled proj4 output)
    //   ybuf : 4 img * 14400*256 bf16  = 29,491,200 B   (K=8 half-chunks; K=4 full fits)
    //   qbuf : 4 img * 14400*512 bf16  = 58,982,400 B   (B box fp32 aliases here)
    //   wbuf : bf16 weights            =    393,216 B
    const size_t S8_B = 8ull * 225 * 256 * 64 * 2;
    const size_t S4_B = 8ull * 256 * 256 * 16 * 2;
    const size_t Y_B  = 4ull * 14400 * 256 * 2;
    const size_t Q_B  = 4ull * 14400 * 512 * 2;
    const size_t W_B  = (512ull * 256 + 256ull * 256) * 2;
    if (ws_size < S8_B + S4_B + Y_B + Q_B + W_B) {
        hipMemsetAsync(d_out, 0x46, 4, stream);  // finite sentinel: ws too small
        return;
    }
    ushort* s8    = (ushort*)d_ws;
    ushort* s4    = s8 + S8_B / 2;
    ushort* ybuf  = s4 + S4_B / 2;
    ushort* qbuf  = ybuf + Y_B / 2;
    ushort* qw_bf = qbuf + Q_B / 2;
    ushort* pw_bf = qw_bf + 512 * 256;
    float*  Bbuf  = (float*)qbuf;   // alias: B dead before qkv written

    f2bf_kernel<<<128, 256, 0, stream>>>(qkv_w, qw_bf);
    f2bf_kernel<<<64, 256, 0, stream>>>(proj_w, pw_bf);

    // K=8 chain (L=15), two halves of 4 images: 4*14400 = 57600 rows = 900 tiles
    for (int hf = 0; hf < 2; ++hf) {
        const float* x_h = x + (size_t)hf * 4 * 256 * 4096;
        ushort* s8_h = s8 + (size_t)hf * 4 * 225 * 256 * 64;
        box_kernel<<<4 * 65, 256, 0, stream>>>(x_h, Bbuf);
        pool_kernel<8, 15><<<4 * 225, 256, 0, stream>>>(Bbuf, dpw, dpb, ybuf);
        gemm_kernel<512, 0, 8, 15><<<dim3(8, 900), 256, 0, stream>>>(ybuf, qw_bf, qkv_b, qbuf);
        attn_kernel<8><<<4 * 225 * 4, 256, 0, stream>>>(qbuf, apw, apb, ybuf);
        gemm_kernel<256, 1, 8, 15><<<dim3(4, 900), 256, 0, stream>>>(ybuf, pw_bf, proj_b, s8_h);
    }
    // K=4 chain (L=16), all 8 images: 8*4096 = 32768 rows = 512 tiles
    box_kernel<<<8 * 65, 256, 0, stream>>>(x, Bbuf);
    pool_kernel<4, 16><<<8 * 256, 256, 0, stream>>>(Bbuf, dpw, dpb, ybuf);
    gemm_kernel<512, 0, 4, 16><<<dim3(8, 512), 256, 0, stream>>>(ybuf, qw_bf, qkv_b, qbuf);
    attn_kernel<4><<<8 * 256 * 4, 256, 0, stream>>>(qbuf, apw, apb, ybuf);
    gemm_kernel<256, 1, 4, 16><<<dim3(4, 512), 256, 0, stream>>>(ybuf, pw_bf, proj_b, s4);

    final_kernel<<<2048, 256, 0, stream>>>(x, s8, s4, out);
}

// Round 7
// 551.943 us; speedup vs baseline: 9.8205x; 1.4597x over previous
//
#include <hip/hip_runtime.h>
#include <hip/hip_bf16.h>

typedef __bf16 bf16x8 __attribute__((ext_vector_type(8)));
typedef float  f32x4  __attribute__((ext_vector_type(4)));

#define DEV static __device__ __forceinline__

DEV float bf2f(ushort u) { unsigned x = ((unsigned)u) << 16; return __uint_as_float(x); }
DEV ushort f2bf(float f) {
    unsigned u = __float_as_uint(f);
    unsigned r = (u + 0x7FFFu + ((u >> 16) & 1u)) >> 16;  // RNE
    return (ushort)r;
}

// ---------------- fp32 -> bf16 weight conversion (one-time, tiny) ----------------
__global__ __launch_bounds__(256) void f2bf_kernel(
    const float* __restrict__ src, ushort* __restrict__ dst)
{
    int i = (blockIdx.x * 256 + threadIdx.x) * 4;
    float4 v = *(const float4*)(src + i);
    ushort4 o;
    o.x = f2bf(v.x); o.y = f2bf(v.y); o.z = f2bf(v.z); o.w = f2bf(v.w);
    *(ushort4*)(dst + i) = o;
}

// ---------------- box filter: B[g][br][bc][256] fp32, br,bc in [0,65) ----------------
__global__ __launch_bounds__(256) void box_kernel(
    const float* __restrict__ x,   // [G][256][64][64] fp32 (group base)
    float* __restrict__ B)         // [G][65][65][256] fp32
{
    int br = blockIdx.x % 65; int g = blockIdx.x / 65;
    const float* xg = x + (size_t)g * 256 * 4096;
    float* Bg = B + (size_t)g * 65 * 65 * 256;
    const int r0 = max(br - 1, 0) * 64;
    const int r1 = min(br, 63) * 64;
    __shared__ float s[128][65];
    const int wl = threadIdx.x & 63, cq = threadIdx.x >> 6;   // load mapping
    const int c2 = threadIdx.x & 127, bh = threadIdx.x >> 7;  // store mapping
    for (int half = 0; half < 2; ++half) {
#pragma unroll 4
        for (int it = 0; it < 32; ++it) {
            int cl_ = it * 4 + cq;
            const float* xp = xg + (size_t)(half * 128 + cl_) * 4096;
            s[cl_][wl] = xp[r0 + wl] + xp[r1 + wl];
        }
        __syncthreads();
        for (int bc = bh; bc < 65; bc += 2) {
            float v = 0.25f * (s[c2][max(bc - 1, 0)] + s[c2][min(bc, 63)]);
            Bg[((size_t)br * 65 + bc) * 256 + half * 128 + c2] = v;
        }
        __syncthreads();
    }
}

// ---------------- pool gather + depthwise 3x3 + residual ----------------
template<int K, int L>
__global__ __launch_bounds__(256) void pool_kernel(
    const float* __restrict__ B,    // [G][65][65][256] fp32
    const float* __restrict__ w9,   // [256][9] fp32
    const float* __restrict__ bias, // [256] fp32
    ushort* __restrict__ y)         // bf16 out
{
    constexpr int HF = K / 2;
    const int pk = blockIdx.x;
    const int lw = pk % L; int t = pk / L; const int lh = t % L; const int g = t / L;
    const int c = threadIdx.x;
    const float* Bg = B + (size_t)g * 65 * 65 * 256 + c;
    float pool[K][K];
#pragma unroll
    for (int p = 0; p < K; ++p) {
        const int br = lh * 4 + p + (p >= HF ? 1 : 0);
#pragma unroll
        for (int q = 0; q < K; ++q) {
            const int bc = lw * 4 + q + (q >= HF ? 1 : 0);
            pool[p][q] = Bg[((size_t)br * 65 + bc) * 256];
        }
    }
    float wv[9];
#pragma unroll
    for (int i = 0; i < 9; ++i) wv[i] = w9[c * 9 + i];
    const float bv = bias[c];
    ushort* yp = y + (size_t)pk * (K * K) * 256 + c;
#pragma unroll
    for (int p = 0; p < K; ++p) {
#pragma unroll
        for (int q = 0; q < K; ++q) {
            float a = pool[p][q] + bv;   // residual + conv bias
#pragma unroll
            for (int dp = -1; dp <= 1; ++dp) {
#pragma unroll
                for (int dq = -1; dq <= 1; ++dq) {
                    int pp = p + dp, qq = q + dq;
                    if (pp >= 0 && pp < K && qq >= 0 && qq < K)
                        a += wv[(dp + 1) * 3 + (dq + 1)] * pool[pp][qq];
                }
            }
            yp[(p * K + q) * 256] = f2bf(a);
        }
    }
}

// ---------------- GEMM: OUT[n][ch] = sum_c ACT[n][c] * W[ch][c] (+bias) ----------------
template<int OC, int EPI, int K, int L>
__global__ __launch_bounds__(256) void gemm_kernel(
    const ushort* __restrict__ act,  // [rows][256] bf16
    const ushort* __restrict__ w,    // [OC][256]  bf16
    const float* __restrict__ bias,  // [OC] fp32
    ushort* __restrict__ out_bf)
{
    __shared__ __attribute__((aligned(16))) ushort As[64][40];
    __shared__ __attribute__((aligned(16))) ushort Ws[64][40];
    const int tid  = threadIdx.x;
    const int ch0  = blockIdx.x * 64;
    const int n0   = blockIdx.y * 64;
    const int wv   = tid >> 6, lane = tid & 63;
    const int ar   = tid >> 2, acs = (tid & 3) * 8;
    f32x4 acc[4] = {};

    const ushort* aptr = act + (size_t)(n0 + ar) * 256 + acs;
    const ushort* wptr = w   + (size_t)(ch0 + ar) * 256 + acs;
    for (int k0 = 0; k0 < 256; k0 += 32) {
        *(uint4*)&As[ar][acs] = *(const uint4*)(aptr + k0);
        *(uint4*)&Ws[ar][acs] = *(const uint4*)(wptr + k0);
        __syncthreads();
        const int mrow = wv * 16 + (lane & 15);
        const int quad = lane >> 4;
        bf16x8 af = *(const bf16x8*)&As[mrow][quad * 8];
#pragma unroll
        for (int ct = 0; ct < 4; ++ct) {
            bf16x8 bfv = *(const bf16x8*)&Ws[ct * 16 + (lane & 15)][quad * 8];
            acc[ct] = __builtin_amdgcn_mfma_f32_16x16x32_bf16(af, bfv, acc[ct], 0, 0, 0);
        }
        __syncthreads();
    }
    const int colL  = lane & 15;
    const int rbase = wv * 16 + (lane >> 4) * 4;
#pragma unroll
    for (int ct = 0; ct < 4; ++ct) {
        int ch = ch0 + ct * 16 + colL;
        float bv = bias[ch];
#pragma unroll
        for (int r = 0; r < 4; ++r) {
            int n = n0 + rbase + r;
            float val = acc[ct][r] + bv;
            if (EPI == 0) {
                out_bf[(size_t)n * OC + ch] = f2bf(val);
            } else {
                constexpr int K2 = K * K;
                constexpr int LL = L * L;
                int b_g   = n >> (K == 8 ? 6 : 4);
                int pq    = n & (K2 - 1);
                int gl    = b_g / LL;
                int b_loc = b_g - gl * LL;
                int f = (b_loc * 256 + ch) * K2 + pq;
                out_bf[(size_t)gl * (256 * K2 * LL) + f] = f2bf(val);
            }
        }
    }
}

// ---------------- MFMA attention for K=8 (NSP=64): block = 1 patch, 2 heads ----------------
// grid = patches*2; block 256 = 4 waves; wave w: head = (blockIdx&1)*2 + (w>>1), strip set ww = w&1.
__global__ __launch_bounds__(256) void attn8_mfma_kernel(
    const ushort* __restrict__ qkv,  // [patches*64][512] bf16
    const float* __restrict__ pe_w,  // [256][9] fp32
    const float* __restrict__ pe_b,  // [256] fp32
    ushort* __restrict__ o_out)      // [patches*64][256] bf16
{
    constexpr float SCALE = 0.17677669529663687f;  // 32^-0.5
    __shared__ __attribute__((aligned(16))) ushort Pl[2][64][72];
    __shared__ __attribute__((aligned(16))) ushort Vt[2][64][72];
    const int tid  = threadIdx.x;
    const int lane = tid & 63;
    const int w    = tid >> 6;
    const int hh   = w >> 1, ww = w & 1;
    const int b    = blockIdx.x >> 1;
    const int h    = (blockIdx.x & 1) * 2 + hh;
    const int l15  = lane & 15, quad = lane >> 4;
    const ushort* base = qkv + (size_t)b * 64 * 512 + h * 128;

    // ---- V load + transpose into Vt[hh][d][m]; this wave covers d in [ww*32, ww*32+32)
    {
        const int m = lane;
        const ushort* vsrc = base + (size_t)m * 512 + 64 + ww * 32;
        const int d0 = ww * 32;
#pragma unroll
        for (int t = 0; t < 4; ++t) {
            uint4 vv = *(const uint4*)(vsrc + t * 8);
            unsigned u[4] = {vv.x, vv.y, vv.z, vv.w};
#pragma unroll
            for (int e = 0; e < 4; ++e) {
                Vt[hh][d0 + t * 8 + e * 2][m]     = (ushort)(u[e] & 0xFFFF);
                Vt[hh][d0 + t * 8 + e * 2 + 1][m] = (ushort)(u[e] >> 16);
            }
        }
    }

    // ---- S = (Q^T K) * SCALE : strips st = ww, ww+2 (16 rows each)
    bf16x8 fq[2];
#pragma unroll
    for (int s = 0; s < 2; ++s) {
        int n = (ww + 2 * s) * 16 + l15;
        fq[s] = *(const bf16x8*)(base + (size_t)n * 512 + quad * 8);
    }
    f32x4 S[2][4];
#pragma unroll
    for (int mt = 0; mt < 4; ++mt) {
        int m = mt * 16 + l15;
        bf16x8 fk = *(const bf16x8*)(base + (size_t)m * 512 + 32 + quad * 8);
#pragma unroll
        for (int s = 0; s < 2; ++s) {
            f32x4 z = {0.f, 0.f, 0.f, 0.f};
            S[s][mt] = __builtin_amdgcn_mfma_f32_16x16x32_bf16(fq[s], fk, z, 0, 0, 0);
        }
    }
    // ---- softmax over m (4 mt regs x 16 lanes) per row n = st*16 + quad*4 + r
#pragma unroll
    for (int s = 0; s < 2; ++s) {
#pragma unroll
        for (int r = 0; r < 4; ++r) {
            float mx = -1e30f;
#pragma unroll
            for (int mt = 0; mt < 4; ++mt) { S[s][mt][r] *= SCALE; mx = fmaxf(mx, S[s][mt][r]); }
            mx = fmaxf(mx, __shfl_xor(mx, 1));
            mx = fmaxf(mx, __shfl_xor(mx, 2));
            mx = fmaxf(mx, __shfl_xor(mx, 4));
            mx = fmaxf(mx, __shfl_xor(mx, 8));
            float sum = 0.f;
#pragma unroll
            for (int mt = 0; mt < 4; ++mt) { float e = __expf(S[s][mt][r] - mx); S[s][mt][r] = e; sum += e; }
            sum += __shfl_xor(sum, 1);
            sum += __shfl_xor(sum, 2);
            sum += __shfl_xor(sum, 4);
            sum += __shfl_xor(sum, 8);
            float inv = 1.f / sum;
            int n = (ww + 2 * s) * 16 + quad * 4 + r;
#pragma unroll
            for (int mt = 0; mt < 4; ++mt)
                Pl[hh][n][mt * 16 + l15] = f2bf(S[s][mt][r] * inv);
        }
    }
    __syncthreads();

    // ---- O acc init = PE (dwconv3 of V) + bias; col d = dt*16+l15, row n = st*16+quad*4+r
    f32x4 O[2][4];
#pragma unroll
    for (int dt = 0; dt < 4; ++dt) {
        const int c = h * 64 + dt * 16 + l15;
        const int dr = dt * 16 + l15;
        float wc[9];
#pragma unroll
        for (int i = 0; i < 9; ++i) wc[i] = pe_w[c * 9 + i];
        const float pb = pe_b[c];
#pragma unroll
        for (int s = 0; s < 2; ++s) {
#pragma unroll
            for (int r = 0; r < 4; ++r) {
                int n = (ww + 2 * s) * 16 + quad * 4 + r;
                int p = n >> 3, q = n & 7;
                float pe = pb;
#pragma unroll
                for (int dp = -1; dp <= 1; ++dp) {
#pragma unroll
                    for (int dq = -1; dq <= 1; ++dq) {
                        int pp = p + dp, qq = q + dq;
                        if (pp >= 0 && pp < 8 && qq >= 0 && qq < 8)
                            pe += wc[(dp + 1) * 3 + (dq + 1)] * bf2f(Vt[hh][dr][pp * 8 + qq]);
                    }
                }
                O[s][dt][r] = pe;
            }
        }
    }
    // ---- O += P · V^T  (K-dim m = 64, 2 k-steps)
#pragma unroll
    for (int ks = 0; ks < 2; ++ks) {
        bf16x8 fp[2], fv[4];
#pragma unroll
        for (int s = 0; s < 2; ++s)
            fp[s] = *(const bf16x8*)&Pl[hh][(ww + 2 * s) * 16 + l15][ks * 32 + quad * 8];
#pragma unroll
        for (int dt = 0; dt < 4; ++dt)
            fv[dt] = *(const bf16x8*)&Vt[hh][dt * 16 + l15][ks * 32 + quad * 8];
#pragma unroll
        for (int s = 0; s < 2; ++s)
#pragma unroll
            for (int dt = 0; dt < 4; ++dt)
                O[s][dt] = __builtin_amdgcn_mfma_f32_16x16x32_bf16(fp[s], fv[dt], O[s][dt], 0, 0, 0);
    }
    // ---- write o_out[n][c]
#pragma unroll
    for (int s = 0; s < 2; ++s) {
#pragma unroll
        for (int r = 0; r < 4; ++r) {
            int n = (ww + 2 * s) * 16 + quad * 4 + r;
            ushort* dst = o_out + (size_t)(b * 64 + n) * 256 + h * 64;
#pragma unroll
            for (int dt = 0; dt < 4; ++dt)
                dst[dt * 16 + l15] = f2bf(O[s][dt][r]);
        }
    }
}

// ---------------- scalar attention (used for K=4) ----------------
template<int K>
__global__ __launch_bounds__(256) void attn_kernel(
    const ushort* __restrict__ qkv,  // [rows][512] bf16
    const float* __restrict__ pe_w,  // [256][9] fp32
    const float* __restrict__ pe_b,  // [256] fp32
    ushort* __restrict__ o_out)      // [rows][256] bf16
{
    constexpr int NSP = K * K;
    constexpr float SCALE = 0.17677669529663687f;  // 32^-0.5
    __shared__ float q_s[32][NSP];
    __shared__ float k_s[32][NSP];
    __shared__ float v_s[64][NSP + 1];
    __shared__ float S[NSP][NSP + 1];
    const int tid = threadIdx.x;
    const int h = blockIdx.x & 3;
    const int b = blockIdx.x >> 2;
    {
        int n0 = tid >> 4;
        int rr = (tid & 15) * 8;
        for (int nb = 0; nb < NSP; nb += 16) {
            int n = nb + n0;
            const ushort* src = qkv + (size_t)(b * NSP + n) * 512 + h * 128 + rr;
            uint4 pk = *(const uint4*)src;
            ushort us[8];
            *(uint4*)us = pk;
#pragma unroll
            for (int j = 0; j < 8; ++j) {
                int r = rr + j;
                float f = bf2f(us[j]);
                if (r < 32) q_s[r][n] = f * SCALE;
                else if (r < 64) k_s[r - 32][n] = f;
                else v_s[r - 64][n] = f;
            }
        }
    }
    __syncthreads();
    for (int idx = tid; idx < NSP * NSP; idx += 256) {
        int n = idx / NSP, m = idx % NSP;
        float a = 0.f;
#pragma unroll
        for (int d = 0; d < 32; ++d) a += q_s[d][n] * k_s[d][m];
        S[n][m] = a;
    }
    __syncthreads();
    for (int n = tid; n < NSP; n += 256) {
        float mx = -1e30f;
        for (int m = 0; m < NSP; ++m) mx = fmaxf(mx, S[n][m]);
        float sum = 0.f;
        for (int m = 0; m < NSP; ++m) { float e = __expf(S[n][m] - mx); S[n][m] = e; sum += e; }
        float inv = 1.f / sum;
        for (int m = 0; m < NSP; ++m) S[n][m] *= inv;
    }
    __syncthreads();
    for (int idx = tid; idx < 64 * NSP; idx += 256) {
        int d = idx & 63, n = idx >> 6;
        float a = 0.f;
        for (int m = 0; m < NSP; ++m) a += v_s[d][m] * S[n][m];
        int c = h * 64 + d;
        int p = n / K, q = n % K;
        float pe = pe_b[c];
        const float* wc = pe_w + c * 9;
#pragma unroll
        for (int dp = -1; dp <= 1; ++dp) {
#pragma unroll
            for (int dq = -1; dq <= 1; ++dq) {
                int pp = p + dp, qq = q + dq;
                if (pp >= 0 && pp < K && qq >= 0 && qq < K)
                    pe += wc[(dp + 1) * 3 + (dq + 1)] * v_s[d][pp * K + qq];
            }
        }
        o_out[(size_t)(b * NSP + n) * 256 + c] = f2bf(a + pe);
    }
}

// ---------------- final: out = (x + fold8(s8) + fold4(s4)) / 3 ----------------
__global__ __launch_bounds__(256) void final_kernel(
    const float* __restrict__ x,
    const ushort* __restrict__ s8,
    const ushort* __restrict__ s4,
    float* __restrict__ out)
{
    const int c2 = blockIdx.x & 255;
    const int g  = blockIdx.x >> 8;
    const ushort* s8g = s8 + (size_t)g * (256 * 64 * 225);
    const ushort* s4g = s4 + (size_t)g * (256 * 16 * 256);
    const float third = 1.f / 3.f;
#pragma unroll 2
    for (int it = 0; it < 16; ++it) {
        int pix = it * 256 + threadIdx.x;       // h*64 + w
        int h = pix >> 6, w = pix & 63;
        int f4 = ((((c2 * 4 + (h & 3)) * 4 + (w & 3)) * 16 + (h >> 2)) * 16) + (w >> 2);
        float v4 = bf2f(s4g[f4]);
        int lh_lo = (h >= 8) ? ((h - 4) >> 2) : 0, lh_hi = min(14, h >> 2);
        int lw_lo = (w >= 8) ? ((w - 4) >> 2) : 0, lw_hi = min(14, w >> 2);
        float v8 = 0.f;
        for (int lh2 = lh_lo; lh2 <= lh_hi; ++lh2) {
            int p2 = h - lh2 * 4;
            for (int lw2 = lw_lo; lw2 <= lw_hi; ++lw2) {
                int q2 = w - lw2 * 4;
                int f8 = (((c2 * 8 + p2) * 8 + q2) * 15 + lh2) * 15 + lw2;
                v8 += bf2f(s8g[f8]);
            }
        }
        float inv = 1.f / (float)((lh_hi - lh_lo + 1) * (lw_hi - lw_lo + 1));
        size_t off = ((size_t)(g * 256 + c2)) * 4096 + pix;
        out[off] = (x[off] + v8 * inv + v4) * third;
    }
}

extern "C" void kernel_launch(void* const* d_in, const int* in_sizes, int n_in,
                              void* d_out, int out_size, void* d_ws, size_t ws_size,
                              hipStream_t stream)
{
    const float* x      = (const float*)d_in[0];
    const float* qkv_w  = (const float*)d_in[1];
    const float* qkv_b  = (const float*)d_in[2];
    const float* proj_w = (const float*)d_in[3];
    const float* proj_b = (const float*)d_in[4];
    const float* apw    = (const float*)d_in[5];
    const float* apb    = (const float*)d_in[6];
    const float* dpw    = (const float*)d_in[7];
    const float* dpb    = (const float*)d_in[8];
    float* out = (float*)d_out;

    const size_t S8_B = 8ull * 225 * 256 * 64 * 2;
    const size_t S4_B = 8ull * 256 * 256 * 16 * 2;
    const size_t Y_B  = 4ull * 14400 * 256 * 2;
    const size_t Q_B  = 4ull * 14400 * 512 * 2;
    const size_t W_B  = (512ull * 256 + 256ull * 256) * 2;
    if (ws_size < S8_B + S4_B + Y_B + Q_B + W_B) {
        hipMemsetAsync(d_out, 0x46, 4, stream);  // finite sentinel: ws too small
        return;
    }
    ushort* s8    = (ushort*)d_ws;
    ushort* s4    = s8 + S8_B / 2;
    ushort* ybuf  = s4 + S4_B / 2;
    ushort* qbuf  = ybuf + Y_B / 2;
    ushort* qw_bf = qbuf + Q_B / 2;
    ushort* pw_bf = qw_bf + 512 * 256;
    float*  Bbuf  = (float*)qbuf;   // alias: B dead before qkv written

    f2bf_kernel<<<128, 256, 0, stream>>>(qkv_w, qw_bf);
    f2bf_kernel<<<64, 256, 0, stream>>>(proj_w, pw_bf);

    // K=8 chain (L=15), two halves of 4 images: 4*14400 = 57600 rows = 900 patches
    for (int hf = 0; hf < 2; ++hf) {
        const float* x_h = x + (size_t)hf * 4 * 256 * 4096;
        ushort* s8_h = s8 + (size_t)hf * 4 * 225 * 256 * 64;
        box_kernel<<<4 * 65, 256, 0, stream>>>(x_h, Bbuf);
        pool_kernel<8, 15><<<4 * 225, 256, 0, stream>>>(Bbuf, dpw, dpb, ybuf);
        gemm_kernel<512, 0, 8, 15><<<dim3(8, 900), 256, 0, stream>>>(ybuf, qw_bf, qkv_b, qbuf);
        attn8_mfma_kernel<<<900 * 2, 256, 0, stream>>>(qbuf, apw, apb, ybuf);
        gemm_kernel<256, 1, 8, 15><<<dim3(4, 900), 256, 0, stream>>>(ybuf, pw_bf, proj_b, s8_h);
    }
    // K=4 chain (L=16), all 8 images: 8*4096 = 32768 rows = 512 tiles
    box_kernel<<<8 * 65, 256, 0, stream>>>(x, Bbuf);
    pool_kernel<4, 16><<<8 * 256, 256, 0, stream>>>(Bbuf, dpw, dpb, ybuf);
    gemm_kernel<512, 0, 4, 16><<<dim3(8, 512), 256, 0, stream>>>(ybuf, qw_bf, qkv_b, qbuf);
    attn_kernel<4><<<8 * 256 * 4, 256, 0, stream>>>(qbuf, apw, apb, ybuf);
    gemm_kernel<256, 1, 4, 16><<<dim3(4, 512), 256, 0, stream>>>(ybuf, pw_bf, proj_b, s4);

    final_kernel<<<2048, 256, 0, stream>>>(x, s8, s4, out);
}

// Round 8
// 550.161 us; speedup vs baseline: 9.8523x; 1.0032x over previous
//
#include <hip/hip_runtime.h>
#include <hip/hip_bf16.h>

typedef __bf16 bf16x8 __attribute__((ext_vector_type(8)));
typedef float  f32x4  __attribute__((ext_vector_type(4)));

#define DEV static __device__ __forceinline__

DEV float bf2f(ushort u) { unsigned x = ((unsigned)u) << 16; return __uint_as_float(x); }
DEV ushort f2bf(float f) {
    unsigned u = __float_as_uint(f);
    unsigned r = (u + 0x7FFFu + ((u >> 16) & 1u)) >> 16;  // RNE
    return (ushort)r;
}

// ---------------- fp32 -> bf16 weight conversion (one-time, tiny) ----------------
__global__ __launch_bounds__(256) void f2bf_kernel(
    const float* __restrict__ src, ushort* __restrict__ dst)
{
    int i = (blockIdx.x * 256 + threadIdx.x) * 4;
    float4 v = *(const float4*)(src + i);
    ushort4 o;
    o.x = f2bf(v.x); o.y = f2bf(v.y); o.z = f2bf(v.z); o.w = f2bf(v.w);
    *(ushort4*)(dst + i) = o;
}

// ---------------- box filter: B[g][br][bc][256] fp32, br,bc in [0,65) ----------------
__global__ __launch_bounds__(256) void box_kernel(
    const float* __restrict__ x,   // [G][256][64][64] fp32 (group base)
    float* __restrict__ B)         // [G][65][65][256] fp32
{
    int br = blockIdx.x % 65; int g = blockIdx.x / 65;
    const float* xg = x + (size_t)g * 256 * 4096;
    float* Bg = B + (size_t)g * 65 * 65 * 256;
    const int r0 = max(br - 1, 0) * 64;
    const int r1 = min(br, 63) * 64;
    __shared__ float s[128][65];
    const int wl = threadIdx.x & 63, cq = threadIdx.x >> 6;   // load mapping
    const int c2 = threadIdx.x & 127, bh = threadIdx.x >> 7;  // store mapping
    for (int half = 0; half < 2; ++half) {
#pragma unroll 4
        for (int it = 0; it < 32; ++it) {
            int cl_ = it * 4 + cq;
            const float* xp = xg + (size_t)(half * 128 + cl_) * 4096;
            s[cl_][wl] = xp[r0 + wl] + xp[r1 + wl];
        }
        __syncthreads();
        for (int bc = bh; bc < 65; bc += 2) {
            float v = 0.25f * (s[c2][max(bc - 1, 0)] + s[c2][min(bc, 63)]);
            Bg[((size_t)br * 65 + bc) * 256 + half * 128 + c2] = v;
        }
        __syncthreads();
    }
}

// ---------------- pool gather + depthwise 3x3 + residual ----------------
template<int K, int L>
__global__ __launch_bounds__(256) void pool_kernel(
    const float* __restrict__ B,    // [G][65][65][256] fp32
    const float* __restrict__ w9,   // [256][9] fp32
    const float* __restrict__ bias, // [256] fp32
    ushort* __restrict__ y)         // bf16 out
{
    constexpr int HF = K / 2;
    const int pk = blockIdx.x;
    const int lw = pk % L; int t = pk / L; const int lh = t % L; const int g = t / L;
    const int c = threadIdx.x;
    const float* Bg = B + (size_t)g * 65 * 65 * 256 + c;
    float pool[K][K];
#pragma unroll
    for (int p = 0; p < K; ++p) {
        const int br = lh * 4 + p + (p >= HF ? 1 : 0);
#pragma unroll
        for (int q = 0; q < K; ++q) {
            const int bc = lw * 4 + q + (q >= HF ? 1 : 0);
            pool[p][q] = Bg[((size_t)br * 65 + bc) * 256];
        }
    }
    float wv[9];
#pragma unroll
    for (int i = 0; i < 9; ++i) wv[i] = w9[c * 9 + i];
    const float bv = bias[c];
    ushort* yp = y + (size_t)pk * (K * K) * 256 + c;
#pragma unroll
    for (int p = 0; p < K; ++p) {
#pragma unroll
        for (int q = 0; q < K; ++q) {
            float a = pool[p][q] + bv;   // residual + conv bias
#pragma unroll
            for (int dp = -1; dp <= 1; ++dp) {
#pragma unroll
                for (int dq = -1; dq <= 1; ++dq) {
                    int pp = p + dp, qq = q + dq;
                    if (pp >= 0 && pp < K && qq >= 0 && qq < K)
                        a += wv[(dp + 1) * 3 + (dq + 1)] * pool[pp][qq];
                }
            }
            yp[(p * K + q) * 256] = f2bf(a);
        }
    }
}

// ---------------- GEMM: OUT[n][ch] = sum_c ACT[n][c] * W[ch][c] (+bias) ----------------
template<int OC, int EPI, int K, int L>
__global__ __launch_bounds__(256) void gemm_kernel(
    const ushort* __restrict__ act,  // [rows][256] bf16
    const ushort* __restrict__ w,    // [OC][256]  bf16
    const float* __restrict__ bias,  // [OC] fp32
    ushort* __restrict__ out_bf)
{
    __shared__ __attribute__((aligned(16))) ushort As[64][40];
    __shared__ __attribute__((aligned(16))) ushort Ws[64][40];
    const int tid  = threadIdx.x;
    const int ch0  = blockIdx.x * 64;
    const int n0   = blockIdx.y * 64;
    const int wv   = tid >> 6, lane = tid & 63;
    const int ar   = tid >> 2, acs = (tid & 3) * 8;
    f32x4 acc[4] = {};

    const ushort* aptr = act + (size_t)(n0 + ar) * 256 + acs;
    const ushort* wptr = w   + (size_t)(ch0 + ar) * 256 + acs;
    for (int k0 = 0; k0 < 256; k0 += 32) {
        *(uint4*)&As[ar][acs] = *(const uint4*)(aptr + k0);
        *(uint4*)&Ws[ar][acs] = *(const uint4*)(wptr + k0);
        __syncthreads();
        const int mrow = wv * 16 + (lane & 15);
        const int quad = lane >> 4;
        bf16x8 af = *(const bf16x8*)&As[mrow][quad * 8];
#pragma unroll
        for (int ct = 0; ct < 4; ++ct) {
            bf16x8 bfv = *(const bf16x8*)&Ws[ct * 16 + (lane & 15)][quad * 8];
            acc[ct] = __builtin_amdgcn_mfma_f32_16x16x32_bf16(af, bfv, acc[ct], 0, 0, 0);
        }
        __syncthreads();
    }
    const int colL  = lane & 15;
    const int rbase = wv * 16 + (lane >> 4) * 4;
#pragma unroll
    for (int ct = 0; ct < 4; ++ct) {
        int ch = ch0 + ct * 16 + colL;
        float bv = bias[ch];
#pragma unroll
        for (int r = 0; r < 4; ++r) {
            int n = n0 + rbase + r;
            float val = acc[ct][r] + bv;
            if (EPI == 0) {
                out_bf[(size_t)n * OC + ch] = f2bf(val);
            } else {
                constexpr int K2 = K * K;
                constexpr int LL = L * L;
                int b_g   = n >> (K == 8 ? 6 : 4);
                int pq    = n & (K2 - 1);
                int gl    = b_g / LL;
                int b_loc = b_g - gl * LL;
                int f = (b_loc * 256 + ch) * K2 + pq;
                out_bf[(size_t)gl * (256 * K2 * LL) + f] = f2bf(val);
            }
        }
    }
}

// ---------------- MFMA attention for K=8 (NSP=64): block = 1 patch, 2 heads ----------------
// grid = patches*2; block 256 = 4 waves; wave w: head = (blockIdx&1)*2 + (w>>1), strip set ww = w&1.
// PE dwconv is a vectorized pre-pass writing bf16 PEsh into the Pl region (dead until P write).
__global__ __launch_bounds__(256) void attn8_mfma_kernel(
    const ushort* __restrict__ qkv,  // [patches*64][512] bf16
    const float* __restrict__ pe_w,  // [256][9] fp32
    const float* __restrict__ pe_b,  // [256] fp32
    ushort* __restrict__ o_out)      // [patches*64][256] bf16
{
    constexpr float SCALE = 0.17677669529663687f;  // 32^-0.5
    __shared__ __attribute__((aligned(16))) ushort Pl[2][64][72];  // PEsh, then P
    __shared__ __attribute__((aligned(16))) ushort Vt[2][64][72];
    __shared__ __attribute__((aligned(16))) ushort wsh[9][128];    // dwconv w, [tap][c-local] bf16
    __shared__ float bsh[128];
    const int tid  = threadIdx.x;
    const int lane = tid & 63;
    const int w    = tid >> 6;
    const int hh   = w >> 1, ww = w & 1;
    const int b    = blockIdx.x >> 1;
    const int hbase = (blockIdx.x & 1) * 2;
    const int cbase = hbase * 64;
    const int h    = hbase + hh;
    const int l15  = lane & 15, quad = lane >> 4;
    const ushort* base = qkv + (size_t)b * 64 * 512 + h * 128;

    // ---- stage dwconv weights (transposed, bf16) + bias
    for (int idx = tid; idx < 9 * 128; idx += 256) {
        int tap = idx >> 7, cl = idx & 127;
        wsh[tap][cl] = f2bf(pe_w[(cbase + cl) * 9 + tap]);
    }
    if (tid < 128) bsh[tid] = pe_b[cbase + tid];

    // ---- V load + transpose into Vt[hh][d][m]; this wave covers d in [ww*32, ww*32+32)
    {
        const int m = lane;
        const ushort* vsrc = base + (size_t)m * 512 + 64 + ww * 32;
        const int d0 = ww * 32;
#pragma unroll
        for (int t = 0; t < 4; ++t) {
            uint4 vv = *(const uint4*)(vsrc + t * 8);
            unsigned u[4] = {vv.x, vv.y, vv.z, vv.w};
#pragma unroll
            for (int e = 0; e < 4; ++e) {
                Vt[hh][d0 + t * 8 + e * 2][m]     = (ushort)(u[e] & 0xFFFF);
                Vt[hh][d0 + t * 8 + e * 2 + 1][m] = (ushort)(u[e] >> 16);
            }
        }
    }

    // ---- S = (Q^T K) * SCALE : strips st = ww, ww+2 (16 rows each)
    bf16x8 fq[2];
#pragma unroll
    for (int s = 0; s < 2; ++s) {
        int n = (ww + 2 * s) * 16 + l15;
        fq[s] = *(const bf16x8*)(base + (size_t)n * 512 + quad * 8);
    }
    f32x4 S[2][4];
#pragma unroll
    for (int mt = 0; mt < 4; ++mt) {
        int m = mt * 16 + l15;
        bf16x8 fk = *(const bf16x8*)(base + (size_t)m * 512 + 32 + quad * 8);
#pragma unroll
        for (int s = 0; s < 2; ++s) {
            f32x4 z = {0.f, 0.f, 0.f, 0.f};
            S[s][mt] = __builtin_amdgcn_mfma_f32_16x16x32_bf16(fq[s], fk, z, 0, 0, 0);
        }
    }
    __syncthreads();   // wsh, bsh, Vt visible

    // ---- PE pre-pass: PEsh[hh2][n][d] = bias + dwconv3(V), 8 channels per thread per item
    {
        const int d8  = (tid & 7) * 8;         // channel slice within head
        const int nb  = (tid >> 3) & 15;       // base row
        const int hh2 = tid >> 7;
        const int h2  = hbase + hh2;
        const int cl0 = hh2 * 64 + d8;
        const ushort* vbase = qkv + (size_t)b * 64 * 512 + h2 * 128 + 64 + d8;
        float pb[8];
#pragma unroll
        for (int e = 0; e < 8; ++e) pb[e] = bsh[cl0 + e];
        uint4 wu[9];
#pragma unroll
        for (int tap = 0; tap < 9; ++tap) wu[tap] = *(const uint4*)&wsh[tap][cl0];
#pragma unroll
        for (int it = 0; it < 4; ++it) {
            const int n = nb + 16 * it;
            const int p = n >> 3, q = n & 7;
            float pe[8];
#pragma unroll
            for (int e = 0; e < 8; ++e) pe[e] = pb[e];
#pragma unroll
            for (int dp = -1; dp <= 1; ++dp) {
#pragma unroll
                for (int dq = -1; dq <= 1; ++dq) {
                    const int pp = p + dp, qq = q + dq;
                    if (pp >= 0 && pp < 8 && qq >= 0 && qq < 8) {
                        const int tap = (dp + 1) * 3 + (dq + 1);
                        uint4 vv = *(const uint4*)(vbase + (size_t)(pp * 8 + qq) * 512);
                        unsigned uv[4] = {vv.x, vv.y, vv.z, vv.w};
                        unsigned uw[4] = {wu[tap].x, wu[tap].y, wu[tap].z, wu[tap].w};
#pragma unroll
                        for (int e2 = 0; e2 < 4; ++e2) {
                            float vlo = __uint_as_float(uv[e2] << 16);
                            float vhi = __uint_as_float(uv[e2] & 0xFFFF0000u);
                            float wlo = __uint_as_float(uw[e2] << 16);
                            float whi = __uint_as_float(uw[e2] & 0xFFFF0000u);
                            pe[2 * e2]     += wlo * vlo;
                            pe[2 * e2 + 1] += whi * vhi;
                        }
                    }
                }
            }
            ushort pk[8];
#pragma unroll
            for (int e = 0; e < 8; ++e) pk[e] = f2bf(pe[e]);
            *(uint4*)&Pl[hh2][n][d8] = *(const uint4*)pk;
        }
    }
    __syncthreads();   // PEsh visible

    // ---- O acc init from PEsh; col d = dt*16+l15, row n = (ww+2s)*16+quad*4+r
    f32x4 O[2][4];
#pragma unroll
    for (int s = 0; s < 2; ++s)
#pragma unroll
        for (int dt = 0; dt < 4; ++dt)
#pragma unroll
            for (int r = 0; r < 4; ++r)
                O[s][dt][r] = bf2f(Pl[hh][(ww + 2 * s) * 16 + quad * 4 + r][dt * 16 + l15]);

    // ---- softmax over m (4 mt regs x 16 lanes) per row, in-register
#pragma unroll
    for (int s = 0; s < 2; ++s) {
#pragma unroll
        for (int r = 0; r < 4; ++r) {
            float mx = -1e30f;
#pragma unroll
            for (int mt = 0; mt < 4; ++mt) { S[s][mt][r] *= SCALE; mx = fmaxf(mx, S[s][mt][r]); }
            mx = fmaxf(mx, __shfl_xor(mx, 1));
            mx = fmaxf(mx, __shfl_xor(mx, 2));
            mx = fmaxf(mx, __shfl_xor(mx, 4));
            mx = fmaxf(mx, __shfl_xor(mx, 8));
            float sum = 0.f;
#pragma unroll
            for (int mt = 0; mt < 4; ++mt) { float e = __expf(S[s][mt][r] - mx); S[s][mt][r] = e; sum += e; }
            sum += __shfl_xor(sum, 1);
            sum += __shfl_xor(sum, 2);
            sum += __shfl_xor(sum, 4);
            sum += __shfl_xor(sum, 8);
            float inv = 1.f / sum;
#pragma unroll
            for (int mt = 0; mt < 4; ++mt) S[s][mt][r] *= inv;
        }
    }
    __syncthreads();   // all PEsh reads done; safe to overwrite Pl with P

    // ---- write P -> Pl
#pragma unroll
    for (int s = 0; s < 2; ++s)
#pragma unroll
        for (int r = 0; r < 4; ++r) {
            int n = (ww + 2 * s) * 16 + quad * 4 + r;
#pragma unroll
            for (int mt = 0; mt < 4; ++mt)
                Pl[hh][n][mt * 16 + l15] = f2bf(S[s][mt][r]);
        }
    __syncthreads();   // Pl visible

    // ---- O += P · V^T  (K-dim m = 64, 2 k-steps)
#pragma unroll
    for (int ks = 0; ks < 2; ++ks) {
        bf16x8 fp[2], fv[4];
#pragma unroll
        for (int s = 0; s < 2; ++s)
            fp[s] = *(const bf16x8*)&Pl[hh][(ww + 2 * s) * 16 + l15][ks * 32 + quad * 8];
#pragma unroll
        for (int dt = 0; dt < 4; ++dt)
            fv[dt] = *(const bf16x8*)&Vt[hh][dt * 16 + l15][ks * 32 + quad * 8];
#pragma unroll
        for (int s = 0; s < 2; ++s)
#pragma unroll
            for (int dt = 0; dt < 4; ++dt)
                O[s][dt] = __builtin_amdgcn_mfma_f32_16x16x32_bf16(fp[s], fv[dt], O[s][dt], 0, 0, 0);
    }
    // ---- write o_out[n][c]
#pragma unroll
    for (int s = 0; s < 2; ++s) {
#pragma unroll
        for (int r = 0; r < 4; ++r) {
            int n = (ww + 2 * s) * 16 + quad * 4 + r;
            ushort* dst = o_out + (size_t)(b * 64 + n) * 256 + h * 64;
#pragma unroll
            for (int dt = 0; dt < 4; ++dt)
                dst[dt * 16 + l15] = f2bf(O[s][dt][r]);
        }
    }
}

// ---------------- scalar attention (used for K=4) ----------------
template<int K>
__global__ __launch_bounds__(256) void attn_kernel(
    const ushort* __restrict__ qkv,  // [rows][512] bf16
    const float* __restrict__ pe_w,  // [256][9] fp32
    const float* __restrict__ pe_b,  // [256] fp32
    ushort* __restrict__ o_out)      // [rows][256] bf16
{
    constexpr int NSP = K * K;
    constexpr float SCALE = 0.17677669529663687f;  // 32^-0.5
    __shared__ float q_s[32][NSP];
    __shared__ float k_s[32][NSP];
    __shared__ float v_s[64][NSP + 1];
    __shared__ float S[NSP][NSP + 1];
    const int tid = threadIdx.x;
    const int h = blockIdx.x & 3;
    const int b = blockIdx.x >> 2;
    {
        int n0 = tid >> 4;
        int rr = (tid & 15) * 8;
        for (int nb = 0; nb < NSP; nb += 16) {
            int n = nb + n0;
            const ushort* src = qkv + (size_t)(b * NSP + n) * 512 + h * 128 + rr;
            uint4 pk = *(const uint4*)src;
            ushort us[8];
            *(uint4*)us = pk;
#pragma unroll
            for (int j = 0; j < 8; ++j) {
                int r = rr + j;
                float f = bf2f(us[j]);
                if (r < 32) q_s[r][n] = f * SCALE;
                else if (r < 64) k_s[r - 32][n] = f;
                else v_s[r - 64][n] = f;
            }
        }
    }
    __syncthreads();
    for (int idx = tid; idx < NSP * NSP; idx += 256) {
        int n = idx / NSP, m = idx % NSP;
        float a = 0.f;
#pragma unroll
        for (int d = 0; d < 32; ++d) a += q_s[d][n] * k_s[d][m];
        S[n][m] = a;
    }
    __syncthreads();
    for (int n = tid; n < NSP; n += 256) {
        float mx = -1e30f;
        for (int m = 0; m < NSP; ++m) mx = fmaxf(mx, S[n][m]);
        float sum = 0.f;
        for (int m = 0; m < NSP; ++m) { float e = __expf(S[n][m] - mx); S[n][m] = e; sum += e; }
        float inv = 1.f / sum;
        for (int m = 0; m < NSP; ++m) S[n][m] *= inv;
    }
    __syncthreads();
    for (int idx = tid; idx < 64 * NSP; idx += 256) {
        int d = idx & 63, n = idx >> 6;
        float a = 0.f;
        for (int m = 0; m < NSP; ++m) a += v_s[d][m] * S[n][m];
        int c = h * 64 + d;
        int p = n / K, q = n % K;
        float pe = pe_b[c];
        const float* wc = pe_w + c * 9;
#pragma unroll
        for (int dp = -1; dp <= 1; ++dp) {
#pragma unroll
            for (int dq = -1; dq <= 1; ++dq) {
                int pp = p + dp, qq = q + dq;
                if (pp >= 0 && pp < K && qq >= 0 && qq < K)
                    pe += wc[(dp + 1) * 3 + (dq + 1)] * v_s[d][pp * K + qq];
            }
        }
        o_out[(size_t)(b * NSP + n) * 256 + c] = f2bf(a + pe);
    }
}

// ---------------- final: out = (x + fold8(s8) + fold4(s4)) / 3 ----------------
__global__ __launch_bounds__(256) void final_kernel(
    const float* __restrict__ x,
    const ushort* __restrict__ s8,
    const ushort* __restrict__ s4,
    float* __restrict__ out)
{
    const int c2 = blockIdx.x & 255;
    const int g  = blockIdx.x >> 8;
    const ushort* s8g = s8 + (size_t)g * (256 * 64 * 225);
    const ushort* s4g = s4 + (size_t)g * (256 * 16 * 256);
    const float third = 1.f / 3.f;
#pragma unroll 2
    for (int it = 0; it < 16; ++it) {
        int pix = it * 256 + threadIdx.x;       // h*64 + w
        int h = pix >> 6, w = pix & 63;
        int f4 = ((((c2 * 4 + (h & 3)) * 4 + (w & 3)) * 16 + (h >> 2)) * 16) + (w >> 2);
        float v4 = bf2f(s4g[f4]);
        int lh_lo = (h >= 8) ? ((h - 4) >> 2) : 0, lh_hi = min(14, h >> 2);
        int lw_lo = (w >= 8) ? ((w - 4) >> 2) : 0, lw_hi = min(14, w >> 2);
        float v8 = 0.f;
        for (int lh2 = lh_lo; lh2 <= lh_hi; ++lh2) {
            int p2 = h - lh2 * 4;
            for (int lw2 = lw_lo; lw2 <= lw_hi; ++lw2) {
                int q2 = w - lw2 * 4;
                int f8 = (((c2 * 8 + p2) * 8 + q2) * 15 + lh2) * 15 + lw2;
                v8 += bf2f(s8g[f8]);
            }
        }
        float inv = 1.f / (float)((lh_hi - lh_lo + 1) * (lw_hi - lw_lo + 1));
        size_t off = ((size_t)(g * 256 + c2)) * 4096 + pix;
        out[off] = (x[off] + v8 * inv + v4) * third;
    }
}

extern "C" void kernel_launch(void* const* d_in, const int* in_sizes, int n_in,
                              void* d_out, int out_size, void* d_ws, size_t ws_size,
                              hipStream_t stream)
{
    const float* x      = (const float*)d_in[0];
    const float* qkv_w  = (const float*)d_in[1];
    const float* qkv_b  = (const float*)d_in[2];
    const float* proj_w = (const float*)d_in[3];
    const float* proj_b = (const float*)d_in[4];
    const float* apw    = (const float*)d_in[5];
    const float* apb    = (const float*)d_in[6];
    const float* dpw    = (const float*)d_in[7];
    const float* dpb    = (const float*)d_in[8];
    float* out = (float*)d_out;

    const size_t S8_B = 8ull * 225 * 256 * 64 * 2;
    const size_t S4_B = 8ull * 256 * 256 * 16 * 2;
    const size_t Y_B  = 4ull * 14400 * 256 * 2;
    const size_t Q_B  = 4ull * 14400 * 512 * 2;
    const size_t W_B  = (512ull * 256 + 256ull * 256) * 2;
    if (ws_size < S8_B + S4_B + Y_B + Q_B + W_B) {
        hipMemsetAsync(d_out, 0x46, 4, stream);  // finite sentinel: ws too small
        return;
    }
    ushort* s8    = (ushort*)d_ws;
    ushort* s4    = s8 + S8_B / 2;
    ushort* ybuf  = s4 + S4_B / 2;
    ushort* qbuf  = ybuf + Y_B / 2;
    ushort* qw_bf = qbuf + Q_B / 2;
    ushort* pw_bf = qw_bf + 512 * 256;
    float*  Bbuf  = (float*)qbuf;   // alias: B dead before qkv written

    f2bf_kernel<<<128, 256, 0, stream>>>(qkv_w, qw_bf);
    f2bf_kernel<<<64, 256, 0, stream>>>(proj_w, pw_bf);

    // K=8 chain (L=15), two halves of 4 images: 4*14400 = 57600 rows = 900 patches
    for (int hf = 0; hf < 2; ++hf) {
        const float* x_h = x + (size_t)hf * 4 * 256 * 4096;
        ushort* s8_h = s8 + (size_t)hf * 4 * 225 * 256 * 64;
        box_kernel<<<4 * 65, 256, 0, stream>>>(x_h, Bbuf);
        pool_kernel<8, 15><<<4 * 225, 256, 0, stream>>>(Bbuf, dpw, dpb, ybuf);
        gemm_kernel<512, 0, 8, 15><<<dim3(8, 900), 256, 0, stream>>>(ybuf, qw_bf, qkv_b, qbuf);
        attn8_mfma_kernel<<<900 * 2, 256, 0, stream>>>(qbuf, apw, apb, ybuf);
        gemm_kernel<256, 1, 8, 15><<<dim3(4, 900), 256, 0, stream>>>(ybuf, pw_bf, proj_b, s8_h);
    }
    // K=4 chain (L=16), all 8 images: 8*4096 = 32768 rows = 512 tiles
    box_kernel<<<8 * 65, 256, 0, stream>>>(x, Bbuf);
    pool_kernel<4, 16><<<8 * 256, 256, 0, stream>>>(Bbuf, dpw, dpb, ybuf);
    gemm_kernel<512, 0, 4, 16><<<dim3(8, 512), 256, 0, stream>>>(ybuf, qw_bf, qkv_b, qbuf);
    attn_kernel<4><<<8 * 256 * 4, 256, 0, stream>>>(qbuf, apw, apb, ybuf);
    gemm_kernel<256, 1, 4, 16><<<dim3(4, 512), 256, 0, stream>>>(ybuf, pw_bf, proj_b, s4);

    final_kernel<<<2048, 256, 0, stream>>>(x, s8, s4, out);
}

// Round 9
// 540.472 us; speedup vs baseline: 10.0289x; 1.0179x over previous
//
#include <hip/hip_runtime.h>
#include <hip/hip_bf16.h>

typedef __bf16 bf16x8 __attribute__((ext_vector_type(8)));
typedef float  f32x4  __attribute__((ext_vector_type(4)));

#define DEV static __device__ __forceinline__

DEV float bf2f(ushort u) { unsigned x = ((unsigned)u) << 16; return __uint_as_float(x); }
DEV ushort f2bf(float f) {
    unsigned u = __float_as_uint(f);
    unsigned r = (u + 0x7FFFu + ((u >> 16) & 1u)) >> 16;  // RNE
    return (ushort)r;
}

// ---------------- fp32 -> bf16 weight conversion (one-time, tiny) ----------------
__global__ __launch_bounds__(256) void f2bf_kernel(
    const float* __restrict__ src, ushort* __restrict__ dst)
{
    int i = (blockIdx.x * 256 + threadIdx.x) * 4;
    float4 v = *(const float4*)(src + i);
    ushort4 o;
    o.x = f2bf(v.x); o.y = f2bf(v.y); o.z = f2bf(v.z); o.w = f2bf(v.w);
    *(ushort4*)(dst + i) = o;
}

// ---------------- box filter: B[g][br][bc][256] fp32, br,bc in [0,65) ----------------
__global__ __launch_bounds__(256) void box_kernel(
    const float* __restrict__ x,   // [8][256][64][64] fp32
    float* __restrict__ B)         // [8][65][65][256] fp32
{
    int br = blockIdx.x % 65; int g = blockIdx.x / 65;
    const float* xg = x + (size_t)g * 256 * 4096;
    float* Bg = B + (size_t)g * 65 * 65 * 256;
    const int r0 = max(br - 1, 0) * 64;
    const int r1 = min(br, 63) * 64;
    __shared__ float s[128][65];
    const int wl = threadIdx.x & 63, cq = threadIdx.x >> 6;   // load mapping
    const int c2 = threadIdx.x & 127, bh = threadIdx.x >> 7;  // store mapping
    for (int half = 0; half < 2; ++half) {
#pragma unroll 4
        for (int it = 0; it < 32; ++it) {
            int cl_ = it * 4 + cq;
            const float* xp = xg + (size_t)(half * 128 + cl_) * 4096;
            s[cl_][wl] = xp[r0 + wl] + xp[r1 + wl];
        }
        __syncthreads();
        for (int bc = bh; bc < 65; bc += 2) {
            float v = 0.25f * (s[c2][max(bc - 1, 0)] + s[c2][min(bc, 63)]);
            Bg[((size_t)br * 65 + bc) * 256 + half * 128 + c2] = v;
        }
        __syncthreads();
    }
}

// ---------------- pool gather + depthwise 3x3 + residual ----------------
template<int K, int L>
__global__ __launch_bounds__(256) void pool_kernel(
    const float* __restrict__ B,    // [G][65][65][256] fp32 (group base)
    const float* __restrict__ w9,   // [256][9] fp32
    const float* __restrict__ bias, // [256] fp32
    ushort* __restrict__ y)         // bf16 out
{
    constexpr int HF = K / 2;
    const int pk = blockIdx.x;
    const int lw = pk % L; int t = pk / L; const int lh = t % L; const int g = t / L;
    const int c = threadIdx.x;
    const float* Bg = B + (size_t)g * 65 * 65 * 256 + c;
    float pool[K][K];
#pragma unroll
    for (int p = 0; p < K; ++p) {
        const int br = lh * 4 + p + (p >= HF ? 1 : 0);
#pragma unroll
        for (int q = 0; q < K; ++q) {
            const int bc = lw * 4 + q + (q >= HF ? 1 : 0);
            pool[p][q] = Bg[((size_t)br * 65 + bc) * 256];
        }
    }
    float wv[9];
#pragma unroll
    for (int i = 0; i < 9; ++i) wv[i] = w9[c * 9 + i];
    const float bv = bias[c];
    ushort* yp = y + (size_t)pk * (K * K) * 256 + c;
#pragma unroll
    for (int p = 0; p < K; ++p) {
#pragma unroll
        for (int q = 0; q < K; ++q) {
            float a = pool[p][q] + bv;   // residual + conv bias
#pragma unroll
            for (int dp = -1; dp <= 1; ++dp) {
#pragma unroll
                for (int dq = -1; dq <= 1; ++dq) {
                    int pp = p + dp, qq = q + dq;
                    if (pp >= 0 && pp < K && qq >= 0 && qq < K)
                        a += wv[(dp + 1) * 3 + (dq + 1)] * pool[pp][qq];
                }
            }
            yp[(p * K + q) * 256] = f2bf(a);
        }
    }
}

// ---------------- GEMM: one block = 64 rows x ALL OC cols (A staged once) ----------------
// EPI==0: store bf16 row-major out_bf[n][OC].
// EPI==1: store bf16 scrambled-f: out_bf[gl*256*K2*LL + (b_loc*256+ch)*K2 + pq].
template<int OC, int EPI, int K, int L>
__global__ __launch_bounds__(256) void gemm_kernel(
    const ushort* __restrict__ act,  // [rows][256] bf16
    const ushort* __restrict__ w,    // [OC][256]  bf16
    const float* __restrict__ bias,  // [OC] fp32
    ushort* __restrict__ out_bf)
{
    __shared__ __attribute__((aligned(16))) ushort As[64][266];  // 133 dwords/row (odd) -> conflict-free
    __shared__ __attribute__((aligned(16))) ushort Ws[64][266];
    const int tid  = threadIdx.x;
    const int n0   = blockIdx.x * 64;
    const int lane = tid & 63;
    const int wv   = tid >> 6;
    const int l15  = lane & 15, quad = lane >> 4;
    const int sr   = tid >> 2;            // staging row 0..63
    const int sc   = tid & 3;             // staging col group

    // ---- stage A (64x256) once
    {
        const ushort* ap = act + (size_t)(n0 + sr) * 256;
#pragma unroll
        for (int i = 0; i < 8; ++i) {
            int col = (sc + i * 4) * 8;
            *(uint4*)&As[sr][col] = *(const uint4*)(ap + col);
        }
    }
    __syncthreads();
    // ---- preload A fragments (ct-invariant): row = wv*16+l15, k-chunk kc
    const int mrow = wv * 16 + l15;
    bf16x8 af[8];
#pragma unroll
    for (int kc = 0; kc < 8; ++kc)
        af[kc] = *(const bf16x8*)&As[mrow][kc * 32 + quad * 8];

    constexpr int NT = OC / 64;
#pragma unroll 1
    for (int ct = 0; ct < NT; ++ct) {
        const int ch0 = ct * 64;
        // stage W tile (64x256)
        {
            const ushort* wp = w + (size_t)(ch0 + sr) * 256;
#pragma unroll
            for (int i = 0; i < 8; ++i) {
                int col = (sc + i * 4) * 8;
                *(uint4*)&Ws[sr][col] = *(const uint4*)(wp + col);
            }
        }
        __syncthreads();
        f32x4 acc[4] = {};
#pragma unroll
        for (int kc = 0; kc < 8; ++kc) {
#pragma unroll
            for (int mt = 0; mt < 4; ++mt) {
                bf16x8 bfv = *(const bf16x8*)&Ws[mt * 16 + l15][kc * 32 + quad * 8];
                acc[mt] = __builtin_amdgcn_mfma_f32_16x16x32_bf16(af[kc], bfv, acc[mt], 0, 0, 0);
            }
        }
        // epilogue for this 64-ch tile
        const int rbase = wv * 16 + (lane >> 4) * 4;
#pragma unroll
        for (int mt = 0; mt < 4; ++mt) {
            int ch = ch0 + mt * 16 + l15;
            float bv = bias[ch];
#pragma unroll
            for (int r = 0; r < 4; ++r) {
                int n = n0 + rbase + r;
                float val = acc[mt][r] + bv;
                if (EPI == 0) {
                    out_bf[(size_t)n * OC + ch] = f2bf(val);
                } else {
                    constexpr int K2 = K * K;
                    constexpr int LL = L * L;
                    int b_g   = n >> (K == 8 ? 6 : 4);
                    int pq    = n & (K2 - 1);
                    int gl    = b_g / LL;
                    int b_loc = b_g - gl * LL;
                    int f = (b_loc * 256 + ch) * K2 + pq;
                    out_bf[(size_t)gl * (256 * K2 * LL) + f] = f2bf(val);
                }
            }
        }
        __syncthreads();   // Ws dead before next stage
    }
}

// ---------------- MFMA attention for K=8 (NSP=64): block = 1 patch, 2 heads ----------------
__global__ __launch_bounds__(256) void attn8_mfma_kernel(
    const ushort* __restrict__ qkv,  // [patches*64][512] bf16
    const float* __restrict__ pe_w,  // [256][9] fp32
    const float* __restrict__ pe_b,  // [256] fp32
    ushort* __restrict__ o_out)      // [patches*64][256] bf16
{
    constexpr float SCALE = 0.17677669529663687f;  // 32^-0.5
    __shared__ __attribute__((aligned(16))) ushort Pl[2][64][72];  // PEsh, then P
    __shared__ __attribute__((aligned(16))) ushort Vt[2][64][72];
    __shared__ __attribute__((aligned(16))) ushort wsh[9][128];    // dwconv w, [tap][c-local] bf16
    __shared__ float bsh[128];
    const int tid  = threadIdx.x;
    const int lane = tid & 63;
    const int w    = tid >> 6;
    const int hh   = w >> 1, ww = w & 1;
    const int b    = blockIdx.x >> 1;
    const int hbase = (blockIdx.x & 1) * 2;
    const int cbase = hbase * 64;
    const int h    = hbase + hh;
    const int l15  = lane & 15, quad = lane >> 4;
    const ushort* base = qkv + (size_t)b * 64 * 512 + h * 128;

    for (int idx = tid; idx < 9 * 128; idx += 256) {
        int tap = idx >> 7, cl = idx & 127;
        wsh[tap][cl] = f2bf(pe_w[(cbase + cl) * 9 + tap]);
    }
    if (tid < 128) bsh[tid] = pe_b[cbase + tid];

    {
        const int m = lane;
        const ushort* vsrc = base + (size_t)m * 512 + 64 + ww * 32;
        const int d0 = ww * 32;
#pragma unroll
        for (int t = 0; t < 4; ++t) {
            uint4 vv = *(const uint4*)(vsrc + t * 8);
            unsigned u[4] = {vv.x, vv.y, vv.z, vv.w};
#pragma unroll
            for (int e = 0; e < 4; ++e) {
                Vt[hh][d0 + t * 8 + e * 2][m]     = (ushort)(u[e] & 0xFFFF);
                Vt[hh][d0 + t * 8 + e * 2 + 1][m] = (ushort)(u[e] >> 16);
            }
        }
    }

    bf16x8 fq[2];
#pragma unroll
    for (int s = 0; s < 2; ++s) {
        int n = (ww + 2 * s) * 16 + l15;
        fq[s] = *(const bf16x8*)(base + (size_t)n * 512 + quad * 8);
    }
    f32x4 S[2][4];
#pragma unroll
    for (int mt = 0; mt < 4; ++mt) {
        int m = mt * 16 + l15;
        bf16x8 fk = *(const bf16x8*)(base + (size_t)m * 512 + 32 + quad * 8);
#pragma unroll
        for (int s = 0; s < 2; ++s) {
            f32x4 z = {0.f, 0.f, 0.f, 0.f};
            S[s][mt] = __builtin_amdgcn_mfma_f32_16x16x32_bf16(fq[s], fk, z, 0, 0, 0);
        }
    }
    __syncthreads();   // wsh, bsh, Vt visible

    {
        const int d8  = (tid & 7) * 8;
        const int nb  = (tid >> 3) & 15;
        const int hh2 = tid >> 7;
        const int h2  = hbase + hh2;
        const int cl0 = hh2 * 64 + d8;
        const ushort* vbase = qkv + (size_t)b * 64 * 512 + h2 * 128 + 64 + d8;
        float pb[8];
#pragma unroll
        for (int e = 0; e < 8; ++e) pb[e] = bsh[cl0 + e];
        uint4 wu[9];
#pragma unroll
        for (int tap = 0; tap < 9; ++tap) wu[tap] = *(const uint4*)&wsh[tap][cl0];
#pragma unroll
        for (int it = 0; it < 4; ++it) {
            const int n = nb + 16 * it;
            const int p = n >> 3, q = n & 7;
            float pe[8];
#pragma unroll
            for (int e = 0; e < 8; ++e) pe[e] = pb[e];
#pragma unroll
            for (int dp = -1; dp <= 1; ++dp) {
#pragma unroll
                for (int dq = -1; dq <= 1; ++dq) {
                    const int pp = p + dp, qq = q + dq;
                    if (pp >= 0 && pp < 8 && qq >= 0 && qq < 8) {
                        const int tap = (dp + 1) * 3 + (dq + 1);
                        uint4 vv = *(const uint4*)(vbase + (size_t)(pp * 8 + qq) * 512);
                        unsigned uv[4] = {vv.x, vv.y, vv.z, vv.w};
                        unsigned uw[4] = {wu[tap].x, wu[tap].y, wu[tap].z, wu[tap].w};
#pragma unroll
                        for (int e2 = 0; e2 < 4; ++e2) {
                            float vlo = __uint_as_float(uv[e2] << 16);
                            float vhi = __uint_as_float(uv[e2] & 0xFFFF0000u);
                            float wlo = __uint_as_float(uw[e2] << 16);
                            float whi = __uint_as_float(uw[e2] & 0xFFFF0000u);
                            pe[2 * e2]     += wlo * vlo;
                            pe[2 * e2 + 1] += whi * vhi;
                        }
                    }
                }
            }
            ushort pk[8];
#pragma unroll
            for (int e = 0; e < 8; ++e) pk[e] = f2bf(pe[e]);
            *(uint4*)&Pl[hh2][n][d8] = *(const uint4*)pk;
        }
    }
    __syncthreads();   // PEsh visible

    f32x4 O[2][4];
#pragma unroll
    for (int s = 0; s < 2; ++s)
#pragma unroll
        for (int dt = 0; dt < 4; ++dt)
#pragma unroll
            for (int r = 0; r < 4; ++r)
                O[s][dt][r] = bf2f(Pl[hh][(ww + 2 * s) * 16 + quad * 4 + r][dt * 16 + l15]);

#pragma unroll
    for (int s = 0; s < 2; ++s) {
#pragma unroll
        for (int r = 0; r < 4; ++r) {
            float mx = -1e30f;
#pragma unroll
            for (int mt = 0; mt < 4; ++mt) { S[s][mt][r] *= SCALE; mx = fmaxf(mx, S[s][mt][r]); }
            mx = fmaxf(mx, __shfl_xor(mx, 1));
            mx = fmaxf(mx, __shfl_xor(mx, 2));
            mx = fmaxf(mx, __shfl_xor(mx, 4));
            mx = fmaxf(mx, __shfl_xor(mx, 8));
            float sum = 0.f;
#pragma unroll
            for (int mt = 0; mt < 4; ++mt) { float e = __expf(S[s][mt][r] - mx); S[s][mt][r] = e; sum += e; }
            sum += __shfl_xor(sum, 1);
            sum += __shfl_xor(sum, 2);
            sum += __shfl_xor(sum, 4);
            sum += __shfl_xor(sum, 8);
            float inv = 1.f / sum;
#pragma unroll
            for (int mt = 0; mt < 4; ++mt) S[s][mt][r] *= inv;
        }
    }
    __syncthreads();   // all PEsh reads done

#pragma unroll
    for (int s = 0; s < 2; ++s)
#pragma unroll
        for (int r = 0; r < 4; ++r) {
            int n = (ww + 2 * s) * 16 + quad * 4 + r;
#pragma unroll
            for (int mt = 0; mt < 4; ++mt)
                Pl[hh][n][mt * 16 + l15] = f2bf(S[s][mt][r]);
        }
    __syncthreads();   // Pl visible

#pragma unroll
    for (int ks = 0; ks < 2; ++ks) {
        bf16x8 fp[2], fv[4];
#pragma unroll
        for (int s = 0; s < 2; ++s)
            fp[s] = *(const bf16x8*)&Pl[hh][(ww + 2 * s) * 16 + l15][ks * 32 + quad * 8];
#pragma unroll
        for (int dt = 0; dt < 4; ++dt)
            fv[dt] = *(const bf16x8*)&Vt[hh][dt * 16 + l15][ks * 32 + quad * 8];
#pragma unroll
        for (int s = 0; s < 2; ++s)
#pragma unroll
            for (int dt = 0; dt < 4; ++dt)
                O[s][dt] = __builtin_amdgcn_mfma_f32_16x16x32_bf16(fp[s], fv[dt], O[s][dt], 0, 0, 0);
    }
#pragma unroll
    for (int s = 0; s < 2; ++s) {
#pragma unroll
        for (int r = 0; r < 4; ++r) {
            int n = (ww + 2 * s) * 16 + quad * 4 + r;
            ushort* dst = o_out + (size_t)(b * 64 + n) * 256 + h * 64;
#pragma unroll
            for (int dt = 0; dt < 4; ++dt)
                dst[dt * 16 + l15] = f2bf(O[s][dt][r]);
        }
    }
}

// ---------------- scalar attention (used for K=4) ----------------
template<int K>
__global__ __launch_bounds__(256) void attn_kernel(
    const ushort* __restrict__ qkv,
    const float* __restrict__ pe_w,
    const float* __restrict__ pe_b,
    ushort* __restrict__ o_out)
{
    constexpr int NSP = K * K;
    constexpr float SCALE = 0.17677669529663687f;
    __shared__ float q_s[32][NSP];
    __shared__ float k_s[32][NSP];
    __shared__ float v_s[64][NSP + 1];
    __shared__ float S[NSP][NSP + 1];
    const int tid = threadIdx.x;
    const int h = blockIdx.x & 3;
    const int b = blockIdx.x >> 2;
    {
        int n0 = tid >> 4;
        int rr = (tid & 15) * 8;
        for (int nb = 0; nb < NSP; nb += 16) {
            int n = nb + n0;
            const ushort* src = qkv + (size_t)(b * NSP + n) * 512 + h * 128 + rr;
            uint4 pk = *(const uint4*)src;
            ushort us[8];
            *(uint4*)us = pk;
#pragma unroll
            for (int j = 0; j < 8; ++j) {
                int r = rr + j;
                float f = bf2f(us[j]);
                if (r < 32) q_s[r][n] = f * SCALE;
                else if (r < 64) k_s[r - 32][n] = f;
                else v_s[r - 64][n] = f;
            }
        }
    }
    __syncthreads();
    for (int idx = tid; idx < NSP * NSP; idx += 256) {
        int n = idx / NSP, m = idx % NSP;
        float a = 0.f;
#pragma unroll
        for (int d = 0; d < 32; ++d) a += q_s[d][n] * k_s[d][m];
        S[n][m] = a;
    }
    __syncthreads();
    for (int n = tid; n < NSP; n += 256) {
        float mx = -1e30f;
        for (int m = 0; m < NSP; ++m) mx = fmaxf(mx, S[n][m]);
        float sum = 0.f;
        for (int m = 0; m < NSP; ++m) { float e = __expf(S[n][m] - mx); S[n][m] = e; sum += e; }
        float inv = 1.f / sum;
        for (int m = 0; m < NSP; ++m) S[n][m] *= inv;
    }
    __syncthreads();
    for (int idx = tid; idx < 64 * NSP; idx += 256) {
        int d = idx & 63, n = idx >> 6;
        float a = 0.f;
        for (int m = 0; m < NSP; ++m) a += v_s[d][m] * S[n][m];
        int c = h * 64 + d;
        int p = n / K, q = n % K;
        float pe = pe_b[c];
        const float* wc = pe_w + c * 9;
#pragma unroll
        for (int dp = -1; dp <= 1; ++dp) {
#pragma unroll
            for (int dq = -1; dq <= 1; ++dq) {
                int pp = p + dp, qq = q + dq;
                if (pp >= 0 && pp < K && qq >= 0 && qq < K)
                    pe += wc[(dp + 1) * 3 + (dq + 1)] * v_s[d][pp * K + qq];
            }
        }
        o_out[(size_t)(b * NSP + n) * 256 + c] = f2bf(a + pe);
    }
}

// ---------------- final: out = (x + fold8(s8) + fold4(s4)) / 3 ----------------
__global__ __launch_bounds__(256) void final_kernel(
    const float* __restrict__ x,
    const ushort* __restrict__ s8,
    const ushort* __restrict__ s4,
    float* __restrict__ out)
{
    const int c2 = blockIdx.x & 255;
    const int g  = blockIdx.x >> 8;
    const ushort* s8g = s8 + (size_t)g * (256 * 64 * 225);
    const ushort* s4g = s4 + (size_t)g * (256 * 16 * 256);
    const float third = 1.f / 3.f;
#pragma unroll 2
    for (int it = 0; it < 16; ++it) {
        int pix = it * 256 + threadIdx.x;       // h*64 + w
        int h = pix >> 6, w = pix & 63;
        int f4 = ((((c2 * 4 + (h & 3)) * 4 + (w & 3)) * 16 + (h >> 2)) * 16) + (w >> 2);
        float v4 = bf2f(s4g[f4]);
        int lh_lo = (h >= 8) ? ((h - 4) >> 2) : 0, lh_hi = min(14, h >> 2);
        int lw_lo = (w >= 8) ? ((w - 4) >> 2) : 0, lw_hi = min(14, w >> 2);
        float v8 = 0.f;
        for (int lh2 = lh_lo; lh2 <= lh_hi; ++lh2) {
            int p2 = h - lh2 * 4;
            for (int lw2 = lw_lo; lw2 <= lw_hi; ++lw2) {
                int q2 = w - lw2 * 4;
                int f8 = (((c2 * 8 + p2) * 8 + q2) * 15 + lh2) * 15 + lw2;
                v8 += bf2f(s8g[f8]);
            }
        }
        float inv = 1.f / (float)((lh_hi - lh_lo + 1) * (lw_hi - lw_lo + 1));
        size_t off = ((size_t)(g * 256 + c2)) * 4096 + pix;
        out[off] = (x[off] + v8 * inv + v4) * third;
    }
}

extern "C" void kernel_launch(void* const* d_in, const int* in_sizes, int n_in,
                              void* d_out, int out_size, void* d_ws, size_t ws_size,
                              hipStream_t stream)
{
    const float* x      = (const float*)d_in[0];
    const float* qkv_w  = (const float*)d_in[1];
    const float* qkv_b  = (const float*)d_in[2];
    const float* proj_w = (const float*)d_in[3];
    const float* proj_b = (const float*)d_in[4];
    const float* apw    = (const float*)d_in[5];
    const float* apb    = (const float*)d_in[6];
    const float* dpw    = (const float*)d_in[7];
    const float* dpb    = (const float*)d_in[8];
    float* out = (float*)d_out;

    // Workspace: s8 59 + s4 16.8 + y 29.5 + q 59 + w 0.4 + B 34.6 = 199.4 MB
    const size_t S8_B = 8ull * 225 * 256 * 64 * 2;
    const size_t S4_B = 8ull * 256 * 256 * 16 * 2;
    const size_t Y_B  = 4ull * 14400 * 256 * 2;
    const size_t Q_B  = 4ull * 14400 * 512 * 2;
    const size_t W_B  = (512ull * 256 + 256ull * 256) * 2;
    const size_t B_B  = 8ull * 65 * 65 * 256 * 4;
    if (ws_size < S8_B + S4_B + Y_B + Q_B + W_B + B_B) {
        hipMemsetAsync(d_out, 0x46, 4, stream);  // finite sentinel: ws too small
        return;
    }
    ushort* s8    = (ushort*)d_ws;
    ushort* s4    = s8 + S8_B / 2;
    ushort* ybuf  = s4 + S4_B / 2;
    ushort* qbuf  = ybuf + Y_B / 2;
    ushort* qw_bf = qbuf + Q_B / 2;
    ushort* pw_bf = qw_bf + 512 * 256;
    float*  Bbuf  = (float*)((char*)d_ws + S8_B + S4_B + Y_B + Q_B + W_B);

    f2bf_kernel<<<128, 256, 0, stream>>>(qkv_w, qw_bf);
    f2bf_kernel<<<64, 256, 0, stream>>>(proj_w, pw_bf);
    box_kernel<<<8 * 65, 256, 0, stream>>>(x, Bbuf);   // all 8 images, once

    // K=8 chain (L=15), two halves of 4 images: 4*14400 = 57600 rows = 900 row-tiles
    for (int hf = 0; hf < 2; ++hf) {
        float* B_h = Bbuf + (size_t)hf * 4 * 65 * 65 * 256;
        ushort* s8_h = s8 + (size_t)hf * 4 * 225 * 256 * 64;
        pool_kernel<8, 15><<<4 * 225, 256, 0, stream>>>(B_h, dpw, dpb, ybuf);
        gemm_kernel<512, 0, 8, 15><<<900, 256, 0, stream>>>(ybuf, qw_bf, qkv_b, qbuf);
        attn8_mfma_kernel<<<900 * 2, 256, 0, stream>>>(qbuf, apw, apb, ybuf);
        gemm_kernel<256, 1, 8, 15><<<900, 256, 0, stream>>>(ybuf, pw_bf, proj_b, s8_h);
    }
    // K=4 chain (L=16), all 8 images: 8*4096 = 32768 rows = 512 row-tiles
    pool_kernel<4, 16><<<8 * 256, 256, 0, stream>>>(Bbuf, dpw, dpb, ybuf);
    gemm_kernel<512, 0, 4, 16><<<512, 256, 0, stream>>>(ybuf, qw_bf, qkv_b, qbuf);
    attn_kernel<4><<<8 * 256 * 4, 256, 0, stream>>>(qbuf, apw, apb, ybuf);
    gemm_kernel<256, 1, 4, 16><<<512, 256, 0, stream>>>(ybuf, pw_bf, proj_b, s4);

    final_kernel<<<2048, 256, 0, stream>>>(x, s8, s4, out);
}

// Round 10
// 491.444 us; speedup vs baseline: 11.0294x; 1.0998x over previous
//
#include <hip/hip_runtime.h>
#include <hip/hip_bf16.h>

typedef __bf16 bf16x8 __attribute__((ext_vector_type(8)));
typedef float  f32x4  __attribute__((ext_vector_type(4)));

#define DEV static __device__ __forceinline__

DEV float bf2f(ushort u) { unsigned x = ((unsigned)u) << 16; return __uint_as_float(x); }
DEV ushort f2bf(float f) {
    unsigned u = __float_as_uint(f);
    unsigned r = (u + 0x7FFFu + ((u >> 16) & 1u)) >> 16;  // RNE
    return (ushort)r;
}

// ---------------- fp32 -> bf16 weight conversion (one-time, tiny) ----------------
__global__ __launch_bounds__(256) void f2bf_kernel(
    const float* __restrict__ src, ushort* __restrict__ dst)
{
    int i = (blockIdx.x * 256 + threadIdx.x) * 4;
    float4 v = *(const float4*)(src + i);
    ushort4 o;
    o.x = f2bf(v.x); o.y = f2bf(v.y); o.z = f2bf(v.z); o.w = f2bf(v.w);
    *(ushort4*)(dst + i) = o;
}

// ---------------- box filter: B[g][br][bc][256] fp32, br,bc in [0,65) ----------------
__global__ __launch_bounds__(256) void box_kernel(
    const float* __restrict__ x,   // [8][256][64][64] fp32
    float* __restrict__ B)         // [8][65][65][256] fp32
{
    int br = blockIdx.x % 65; int g = blockIdx.x / 65;
    const float* xg = x + (size_t)g * 256 * 4096;
    float* Bg = B + (size_t)g * 65 * 65 * 256;
    const int r0 = max(br - 1, 0) * 64;
    const int r1 = min(br, 63) * 64;
    __shared__ float s[128][65];
    const int wl = threadIdx.x & 63, cq = threadIdx.x >> 6;   // load mapping
    const int c2 = threadIdx.x & 127, bh = threadIdx.x >> 7;  // store mapping
    for (int half = 0; half < 2; ++half) {
#pragma unroll 4
        for (int it = 0; it < 32; ++it) {
            int cl_ = it * 4 + cq;
            const float* xp = xg + (size_t)(half * 128 + cl_) * 4096;
            s[cl_][wl] = xp[r0 + wl] + xp[r1 + wl];
        }
        __syncthreads();
        for (int bc = bh; bc < 65; bc += 2) {
            float v = 0.25f * (s[c2][max(bc - 1, 0)] + s[c2][min(bc, 63)]);
            Bg[((size_t)br * 65 + bc) * 256 + half * 128 + c2] = v;
        }
        __syncthreads();
    }
}

// ---------------- pool gather + depthwise 3x3 + residual ----------------
template<int K, int L>
__global__ __launch_bounds__(256) void pool_kernel(
    const float* __restrict__ B,    // [G][65][65][256] fp32 (group base)
    const float* __restrict__ w9,   // [256][9] fp32
    const float* __restrict__ bias, // [256] fp32
    ushort* __restrict__ y)         // bf16 out
{
    constexpr int HF = K / 2;
    const int pk = blockIdx.x;
    const int lw = pk % L; int t = pk / L; const int lh = t % L; const int g = t / L;
    const int c = threadIdx.x;
    const float* Bg = B + (size_t)g * 65 * 65 * 256 + c;
    float pool[K][K];
#pragma unroll
    for (int p = 0; p < K; ++p) {
        const int br = lh * 4 + p + (p >= HF ? 1 : 0);
#pragma unroll
        for (int q = 0; q < K; ++q) {
            const int bc = lw * 4 + q + (q >= HF ? 1 : 0);
            pool[p][q] = Bg[((size_t)br * 65 + bc) * 256];
        }
    }
    float wv[9];
#pragma unroll
    for (int i = 0; i < 9; ++i) wv[i] = w9[c * 9 + i];
    const float bv = bias[c];
    ushort* yp = y + (size_t)pk * (K * K) * 256 + c;
#pragma unroll
    for (int p = 0; p < K; ++p) {
#pragma unroll
        for (int q = 0; q < K; ++q) {
            float a = pool[p][q] + bv;   // residual + conv bias
#pragma unroll
            for (int dp = -1; dp <= 1; ++dp) {
#pragma unroll
                for (int dq = -1; dq <= 1; ++dq) {
                    int pp = p + dp, qq = q + dq;
                    if (pp >= 0 && pp < K && qq >= 0 && qq < K)
                        a += wv[(dp + 1) * 3 + (dq + 1)] * pool[pp][qq];
                }
            }
            yp[(p * K + q) * 256] = f2bf(a);
        }
    }
}

// ---------------- GEMM 64x64 tiles, XCD-aware swizzle + LDS XOR swizzle ----------------
// id = t*(8*NT) + k*8 + x : row-tile = t*8+x, ch-tile = k  => all ch-tiles of a row
// share id%8 (same XCD) -> A-tile fetched once per owning XCD's L2.
// LDS 16B-group XOR swizzle (group ^= row&3) kills the 8-way staging-write conflict.
template<int OC, int EPI, int K, int L, int RT>
__global__ __launch_bounds__(256) void gemm_kernel(
    const ushort* __restrict__ act,  // [rows][256] bf16
    const ushort* __restrict__ w,    // [OC][256]  bf16
    const float* __restrict__ bias,  // [OC] fp32
    ushort* __restrict__ out_bf)
{
    __shared__ __attribute__((aligned(16))) ushort As[64][40];
    __shared__ __attribute__((aligned(16))) ushort Ws[64][40];
    constexpr int NT = OC / 64;
    const int id  = blockIdx.x;
    const int xc  = id & 7;
    const int ctb = (id >> 3) % NT;
    const int tt  = id / (8 * NT);
    const int rowt = tt * 8 + xc;
    if (rowt >= RT) return;
    const int tid  = threadIdx.x;
    const int n0   = rowt * 64;
    const int ch0  = ctb * 64;
    const int wv   = tid >> 6, lane = tid & 63;
    const int l15  = lane & 15, quad = lane >> 4;
    const int ar   = tid >> 2, g = tid & 3;
    const int scol = ((g ^ (ar & 3)) * 8);     // swizzled staging col
    f32x4 acc[4] = {};

    const ushort* aptr = act + (size_t)(n0 + ar) * 256 + g * 8;
    const ushort* wptr = w   + (size_t)(ch0 + ar) * 256 + g * 8;
    const int mrow = wv * 16 + l15;
    const int aswz = ((quad ^ (mrow & 3)) * 8);
    for (int k0 = 0; k0 < 256; k0 += 32) {
        *(uint4*)&As[ar][scol] = *(const uint4*)(aptr + k0);
        *(uint4*)&Ws[ar][scol] = *(const uint4*)(wptr + k0);
        __syncthreads();
        bf16x8 af = *(const bf16x8*)&As[mrow][aswz];
#pragma unroll
        for (int mt = 0; mt < 4; ++mt) {
            const int brow = mt * 16 + l15;
            bf16x8 bfv = *(const bf16x8*)&Ws[brow][((quad ^ (brow & 3)) * 8)];
            acc[mt] = __builtin_amdgcn_mfma_f32_16x16x32_bf16(af, bfv, acc[mt], 0, 0, 0);
        }
        __syncthreads();
    }
    const int rbase = wv * 16 + quad * 4;
#pragma unroll
    for (int mt = 0; mt < 4; ++mt) {
        int ch = ch0 + mt * 16 + l15;
        float bv = bias[ch];
#pragma unroll
        for (int r = 0; r < 4; ++r) {
            int n = n0 + rbase + r;
            float val = acc[mt][r] + bv;
            if (EPI == 0) {
                out_bf[(size_t)n * OC + ch] = f2bf(val);
            } else {
                constexpr int K2 = K * K;
                constexpr int LL = L * L;
                int b_g   = n >> (K == 8 ? 6 : 4);
                int pq    = n & (K2 - 1);
                int gl    = b_g / LL;
                int b_loc = b_g - gl * LL;
                int f = (b_loc * 256 + ch) * K2 + pq;
                out_bf[(size_t)gl * (256 * K2 * LL) + f] = f2bf(val);
            }
        }
    }
}

// ---------------- MFMA attention for K=8 (NSP=64): block = 1 patch, 2 heads ----------------
__global__ __launch_bounds__(256) void attn8_mfma_kernel(
    const ushort* __restrict__ qkv,  // [patches*64][512] bf16
    const float* __restrict__ pe_w,  // [256][9] fp32
    const float* __restrict__ pe_b,  // [256] fp32
    ushort* __restrict__ o_out)      // [patches*64][256] bf16
{
    constexpr float SCALE = 0.17677669529663687f;  // 32^-0.5
    __shared__ __attribute__((aligned(16))) ushort Pl[2][64][72];  // PEsh, then P
    __shared__ __attribute__((aligned(16))) ushort Vt[2][64][72];
    __shared__ __attribute__((aligned(16))) ushort wsh[9][128];    // dwconv w, [tap][c-local] bf16
    __shared__ float bsh[128];
    const int tid  = threadIdx.x;
    const int lane = tid & 63;
    const int w    = tid >> 6;
    const int hh   = w >> 1, ww = w & 1;
    const int b    = blockIdx.x >> 1;
    const int hbase = (blockIdx.x & 1) * 2;
    const int cbase = hbase * 64;
    const int h    = hbase + hh;
    const int l15  = lane & 15, quad = lane >> 4;
    const ushort* base = qkv + (size_t)b * 64 * 512 + h * 128;

    for (int idx = tid; idx < 9 * 128; idx += 256) {
        int tap = idx >> 7, cl = idx & 127;
        wsh[tap][cl] = f2bf(pe_w[(cbase + cl) * 9 + tap]);
    }
    if (tid < 128) bsh[tid] = pe_b[cbase + tid];

    {
        const int m = lane;
        const ushort* vsrc = base + (size_t)m * 512 + 64 + ww * 32;
        const int d0 = ww * 32;
#pragma unroll
        for (int t = 0; t < 4; ++t) {
            uint4 vv = *(const uint4*)(vsrc + t * 8);
            unsigned u[4] = {vv.x, vv.y, vv.z, vv.w};
#pragma unroll
            for (int e = 0; e < 4; ++e) {
                Vt[hh][d0 + t * 8 + e * 2][m]     = (ushort)(u[e] & 0xFFFF);
                Vt[hh][d0 + t * 8 + e * 2 + 1][m] = (ushort)(u[e] >> 16);
            }
        }
    }

    bf16x8 fq[2];
#pragma unroll
    for (int s = 0; s < 2; ++s) {
        int n = (ww + 2 * s) * 16 + l15;
        fq[s] = *(const bf16x8*)(base + (size_t)n * 512 + quad * 8);
    }
    f32x4 S[2][4];
#pragma unroll
    for (int mt = 0; mt < 4; ++mt) {
        int m = mt * 16 + l15;
        bf16x8 fk = *(const bf16x8*)(base + (size_t)m * 512 + 32 + quad * 8);
#pragma unroll
        for (int s = 0; s < 2; ++s) {
            f32x4 z = {0.f, 0.f, 0.f, 0.f};
            S[s][mt] = __builtin_amdgcn_mfma_f32_16x16x32_bf16(fq[s], fk, z, 0, 0, 0);
        }
    }
    __syncthreads();   // wsh, bsh, Vt visible

    {
        const int d8  = (tid & 7) * 8;
        const int nb  = (tid >> 3) & 15;
        const int hh2 = tid >> 7;
        const int h2  = hbase + hh2;
        const int cl0 = hh2 * 64 + d8;
        const ushort* vbase = qkv + (size_t)b * 64 * 512 + h2 * 128 + 64 + d8;
        float pb[8];
#pragma unroll
        for (int e = 0; e < 8; ++e) pb[e] = bsh[cl0 + e];
        uint4 wu[9];
#pragma unroll
        for (int tap = 0; tap < 9; ++tap) wu[tap] = *(const uint4*)&wsh[tap][cl0];
#pragma unroll
        for (int it = 0; it < 4; ++it) {
            const int n = nb + 16 * it;
            const int p = n >> 3, q = n & 7;
            float pe[8];
#pragma unroll
            for (int e = 0; e < 8; ++e) pe[e] = pb[e];
#pragma unroll
            for (int dp = -1; dp <= 1; ++dp) {
#pragma unroll
                for (int dq = -1; dq <= 1; ++dq) {
                    const int pp = p + dp, qq = q + dq;
                    if (pp >= 0 && pp < 8 && qq >= 0 && qq < 8) {
                        const int tap = (dp + 1) * 3 + (dq + 1);
                        uint4 vv = *(const uint4*)(vbase + (size_t)(pp * 8 + qq) * 512);
                        unsigned uv[4] = {vv.x, vv.y, vv.z, vv.w};
                        unsigned uw[4] = {wu[tap].x, wu[tap].y, wu[tap].z, wu[tap].w};
#pragma unroll
                        for (int e2 = 0; e2 < 4; ++e2) {
                            float vlo = __uint_as_float(uv[e2] << 16);
                            float vhi = __uint_as_float(uv[e2] & 0xFFFF0000u);
                            float wlo = __uint_as_float(uw[e2] << 16);
                            float whi = __uint_as_float(uw[e2] & 0xFFFF0000u);
                            pe[2 * e2]     += wlo * vlo;
                            pe[2 * e2 + 1] += whi * vhi;
                        }
                    }
                }
            }
            ushort pk[8];
#pragma unroll
            for (int e = 0; e < 8; ++e) pk[e] = f2bf(pe[e]);
            *(uint4*)&Pl[hh2][n][d8] = *(const uint4*)pk;
        }
    }
    __syncthreads();   // PEsh visible

    f32x4 O[2][4];
#pragma unroll
    for (int s = 0; s < 2; ++s)
#pragma unroll
        for (int dt = 0; dt < 4; ++dt)
#pragma unroll
            for (int r = 0; r < 4; ++r)
                O[s][dt][r] = bf2f(Pl[hh][(ww + 2 * s) * 16 + quad * 4 + r][dt * 16 + l15]);

#pragma unroll
    for (int s = 0; s < 2; ++s) {
#pragma unroll
        for (int r = 0; r < 4; ++r) {
            float mx = -1e30f;
#pragma unroll
            for (int mt = 0; mt < 4; ++mt) { S[s][mt][r] *= SCALE; mx = fmaxf(mx, S[s][mt][r]); }
            mx = fmaxf(mx, __shfl_xor(mx, 1));
            mx = fmaxf(mx, __shfl_xor(mx, 2));
            mx = fmaxf(mx, __shfl_xor(mx, 4));
            mx = fmaxf(mx, __shfl_xor(mx, 8));
            float sum = 0.f;
#pragma unroll
            for (int mt = 0; mt < 4; ++mt) { float e = __expf(S[s][mt][r] - mx); S[s][mt][r] = e; sum += e; }
            sum += __shfl_xor(sum, 1);
            sum += __shfl_xor(sum, 2);
            sum += __shfl_xor(sum, 4);
            sum += __shfl_xor(sum, 8);
            float inv = 1.f / sum;
#pragma unroll
            for (int mt = 0; mt < 4; ++mt) S[s][mt][r] *= inv;
        }
    }
    __syncthreads();   // all PEsh reads done

#pragma unroll
    for (int s = 0; s < 2; ++s)
#pragma unroll
        for (int r = 0; r < 4; ++r) {
            int n = (ww + 2 * s) * 16 + quad * 4 + r;
#pragma unroll
            for (int mt = 0; mt < 4; ++mt)
                Pl[hh][n][mt * 16 + l15] = f2bf(S[s][mt][r]);
        }
    __syncthreads();   // Pl visible

#pragma unroll
    for (int ks = 0; ks < 2; ++ks) {
        bf16x8 fp[2], fv[4];
#pragma unroll
        for (int s = 0; s < 2; ++s)
            fp[s] = *(const bf16x8*)&Pl[hh][(ww + 2 * s) * 16 + l15][ks * 32 + quad * 8];
#pragma unroll
        for (int dt = 0; dt < 4; ++dt)
            fv[dt] = *(const bf16x8*)&Vt[hh][dt * 16 + l15][ks * 32 + quad * 8];
#pragma unroll
        for (int s = 0; s < 2; ++s)
#pragma unroll
            for (int dt = 0; dt < 4; ++dt)
                O[s][dt] = __builtin_amdgcn_mfma_f32_16x16x32_bf16(fp[s], fv[dt], O[s][dt], 0, 0, 0);
    }
#pragma unroll
    for (int s = 0; s < 2; ++s) {
#pragma unroll
        for (int r = 0; r < 4; ++r) {
            int n = (ww + 2 * s) * 16 + quad * 4 + r;
            ushort* dst = o_out + (size_t)(b * 64 + n) * 256 + h * 64;
#pragma unroll
            for (int dt = 0; dt < 4; ++dt)
                dst[dt * 16 + l15] = f2bf(O[s][dt][r]);
        }
    }
}

// ---------------- scalar attention (used for K=4) ----------------
template<int K>
__global__ __launch_bounds__(256) void attn_kernel(
    const ushort* __restrict__ qkv,
    const float* __restrict__ pe_w,
    const float* __restrict__ pe_b,
    ushort* __restrict__ o_out)
{
    constexpr int NSP = K * K;
    constexpr float SCALE = 0.17677669529663687f;
    __shared__ float q_s[32][NSP];
    __shared__ float k_s[32][NSP];
    __shared__ float v_s[64][NSP + 1];
    __shared__ float S[NSP][NSP + 1];
    const int tid = threadIdx.x;
    const int h = blockIdx.x & 3;
    const int b = blockIdx.x >> 2;
    {
        int n0 = tid >> 4;
        int rr = (tid & 15) * 8;
        for (int nb = 0; nb < NSP; nb += 16) {
            int n = nb + n0;
            const ushort* src = qkv + (size_t)(b * NSP + n) * 512 + h * 128 + rr;
            uint4 pk = *(const uint4*)src;
            ushort us[8];
            *(uint4*)us = pk;
#pragma unroll
            for (int j = 0; j < 8; ++j) {
                int r = rr + j;
                float f = bf2f(us[j]);
                if (r < 32) q_s[r][n] = f * SCALE;
                else if (r < 64) k_s[r - 32][n] = f;
                else v_s[r - 64][n] = f;
            }
        }
    }
    __syncthreads();
    for (int idx = tid; idx < NSP * NSP; idx += 256) {
        int n = idx / NSP, m = idx % NSP;
        float a = 0.f;
#pragma unroll
        for (int d = 0; d < 32; ++d) a += q_s[d][n] * k_s[d][m];
        S[n][m] = a;
    }
    __syncthreads();
    for (int n = tid; n < NSP; n += 256) {
        float mx = -1e30f;
        for (int m = 0; m < NSP; ++m) mx = fmaxf(mx, S[n][m]);
        float sum = 0.f;
        for (int m = 0; m < NSP; ++m) { float e = __expf(S[n][m] - mx); S[n][m] = e; sum += e; }
        float inv = 1.f / sum;
        for (int m = 0; m < NSP; ++m) S[n][m] *= inv;
    }
    __syncthreads();
    for (int idx = tid; idx < 64 * NSP; idx += 256) {
        int d = idx & 63, n = idx >> 6;
        float a = 0.f;
        for (int m = 0; m < NSP; ++m) a += v_s[d][m] * S[n][m];
        int c = h * 64 + d;
        int p = n / K, q = n % K;
        float pe = pe_b[c];
        const float* wc = pe_w + c * 9;
#pragma unroll
        for (int dp = -1; dp <= 1; ++dp) {
#pragma unroll
            for (int dq = -1; dq <= 1; ++dq) {
                int pp = p + dp, qq = q + dq;
                if (pp >= 0 && pp < K && qq >= 0 && qq < K)
                    pe += wc[(dp + 1) * 3 + (dq + 1)] * v_s[d][pp * K + qq];
            }
        }
        o_out[(size_t)(b * NSP + n) * 256 + c] = f2bf(a + pe);
    }
}

// ---------------- final: out = (x + fold8(s8) + fold4(s4)) / 3 ----------------
__global__ __launch_bounds__(256) void final_kernel(
    const float* __restrict__ x,
    const ushort* __restrict__ s8,
    const ushort* __restrict__ s4,
    float* __restrict__ out)
{
    const int c2 = blockIdx.x & 255;
    const int g  = blockIdx.x >> 8;
    const ushort* s8g = s8 + (size_t)g * (256 * 64 * 225);
    const ushort* s4g = s4 + (size_t)g * (256 * 16 * 256);
    const float third = 1.f / 3.f;
#pragma unroll 2
    for (int it = 0; it < 16; ++it) {
        int pix = it * 256 + threadIdx.x;       // h*64 + w
        int h = pix >> 6, w = pix & 63;
        int f4 = ((((c2 * 4 + (h & 3)) * 4 + (w & 3)) * 16 + (h >> 2)) * 16) + (w >> 2);
        float v4 = bf2f(s4g[f4]);
        int lh_lo = (h >= 8) ? ((h - 4) >> 2) : 0, lh_hi = min(14, h >> 2);
        int lw_lo = (w >= 8) ? ((w - 4) >> 2) : 0, lw_hi = min(14, w >> 2);
        float v8 = 0.f;
        for (int lh2 = lh_lo; lh2 <= lh_hi; ++lh2) {
            int p2 = h - lh2 * 4;
            for (int lw2 = lw_lo; lw2 <= lw_hi; ++lw2) {
                int q2 = w - lw2 * 4;
                int f8 = (((c2 * 8 + p2) * 8 + q2) * 15 + lh2) * 15 + lw2;
                v8 += bf2f(s8g[f8]);
            }
        }
        float inv = 1.f / (float)((lh_hi - lh_lo + 1) * (lw_hi - lw_lo + 1));
        size_t off = ((size_t)(g * 256 + c2)) * 4096 + pix;
        out[off] = (x[off] + v8 * inv + v4) * third;
    }
}

extern "C" void kernel_launch(void* const* d_in, const int* in_sizes, int n_in,
                              void* d_out, int out_size, void* d_ws, size_t ws_size,
                              hipStream_t stream)
{
    const float* x      = (const float*)d_in[0];
    const float* qkv_w  = (const float*)d_in[1];
    const float* qkv_b  = (const float*)d_in[2];
    const float* proj_w = (const float*)d_in[3];
    const float* proj_b = (const float*)d_in[4];
    const float* apw    = (const float*)d_in[5];
    const float* apb    = (const float*)d_in[6];
    const float* dpw    = (const float*)d_in[7];
    const float* dpb    = (const float*)d_in[8];
    float* out = (float*)d_out;

    // Workspace: s8 59 + s4 16.8 + y 29.5 + q 59 + w 0.4 + B 34.6 = 199.4 MB
    const size_t S8_B = 8ull * 225 * 256 * 64 * 2;
    const size_t S4_B = 8ull * 256 * 256 * 16 * 2;
    const size_t Y_B  = 4ull * 14400 * 256 * 2;
    const size_t Q_B  = 4ull * 14400 * 512 * 2;
    const size_t W_B  = (512ull * 256 + 256ull * 256) * 2;
    const size_t B_B  = 8ull * 65 * 65 * 256 * 4;
    if (ws_size < S8_B + S4_B + Y_B + Q_B + W_B + B_B) {
        hipMemsetAsync(d_out, 0x46, 4, stream);  // finite sentinel: ws too small
        return;
    }
    ushort* s8    = (ushort*)d_ws;
    ushort* s4    = s8 + S8_B / 2;
    ushort* ybuf  = s4 + S4_B / 2;
    ushort* qbuf  = ybuf + Y_B / 2;
    ushort* qw_bf = qbuf + Q_B / 2;
    ushort* pw_bf = qw_bf + 512 * 256;
    float*  Bbuf  = (float*)((char*)d_ws + S8_B + S4_B + Y_B + Q_B + W_B);

    f2bf_kernel<<<128, 256, 0, stream>>>(qkv_w, qw_bf);
    f2bf_kernel<<<64, 256, 0, stream>>>(proj_w, pw_bf);
    box_kernel<<<8 * 65, 256, 0, stream>>>(x, Bbuf);   // all 8 images, once

    // K=8 chain (L=15), two halves of 4 images: 4*14400 = 57600 rows = 900 row-tiles
    // grids: ceil(900/8)=113 -> qkv 113*64=7232 blocks, proj 113*32=3616 blocks
    for (int hf = 0; hf < 2; ++hf) {
        float* B_h = Bbuf + (size_t)hf * 4 * 65 * 65 * 256;
        ushort* s8_h = s8 + (size_t)hf * 4 * 225 * 256 * 64;
        pool_kernel<8, 15><<<4 * 225, 256, 0, stream>>>(B_h, dpw, dpb, ybuf);
        gemm_kernel<512, 0, 8, 15, 900><<<7232, 256, 0, stream>>>(ybuf, qw_bf, qkv_b, qbuf);
        attn8_mfma_kernel<<<900 * 2, 256, 0, stream>>>(qbuf, apw, apb, ybuf);
        gemm_kernel<256, 1, 8, 15, 900><<<3616, 256, 0, stream>>>(ybuf, pw_bf, proj_b, s8_h);
    }
    // K=4 chain (L=16), all 8 images: 8*4096 = 32768 rows = 512 row-tiles
    pool_kernel<4, 16><<<8 * 256, 256, 0, stream>>>(Bbuf, dpw, dpb, ybuf);
    gemm_kernel<512, 0, 4, 16, 512><<<4096, 256, 0, stream>>>(ybuf, qw_bf, qkv_b, qbuf);
    attn_kernel<4><<<8 * 256 * 4, 256, 0, stream>>>(qbuf, apw, apb, ybuf);
    gemm_kernel<256, 1, 4, 16, 512><<<2048, 256, 0, stream>>>(ybuf, pw_bf, proj_b, s4);

    final_kernel<<<2048, 256, 0, stream>>>(x, s8, s4, out);
}